// Round 4
// baseline (3457.548 us; speedup 1.0000x reference)
//
#include <hip/hip_runtime.h>
#include <hip/hip_bf16.h>
#include <math.h>
#include <stdint.h>

using bf16 = __hip_bfloat16;
typedef __attribute__((ext_vector_type(8))) short short8;   // 8 bf16 = 4 VGPRs (MFMA A/B frag)
typedef __attribute__((ext_vector_type(4))) float floatx4;  // MFMA C/D frag

typedef const __attribute__((address_space(1))) void* gptr_t;
typedef __attribute__((address_space(3))) void* lptr_t;

// async global->LDS, 16B per lane. Global addr is per-lane; LDS dest is
// wave-uniform base + lane*16 (our per-lane lds ptrs are exactly that).
__device__ __forceinline__ void load_lds16(const bf16* g, bf16* l) {
    __builtin_amdgcn_global_load_lds((gptr_t)(uintptr_t)(const void*)g,
                                     (lptr_t)(uintptr_t)(void*)l, 16, 0, 0);
}

// wait until at most N vector-memory ops outstanding (lgkm/exp untouched)
#define WAIT_VM(n) __builtin_amdgcn_s_waitcnt(0x0F70 | (n))

// tanh(x) = 1 - 2/(exp(2x)+1); saturates correctly at +-inf; err << bf16 ulp.
__device__ __forceinline__ float fast_tanh(float x) {
    float e = __expf(2.f * x);
    return 1.f - 2.f / (e + 1.f);
}

// ---------------------------------------------------------------------------
// Direct-B GEMM + bias + tanh (layers 1 & 2).
// C[m][n] = sum_k A[m][k]*W[n][k].  A (M,K) bf16 row-major, staged via LDS
// (double-buffered, manual barriers).  W pre-permuted to B-frag order:
// tile(nt,kt) of 16(n)x32(k) stored as 64 lanes x 16 B contiguous -> B-frags
// are coalesced global loads on the VMEM pipe (weights are L2-resident).
// Block 128x256, 4 waves (2m x 2n), wave tile 64x128 (MT=4, NT=8).
// Per k32-step/wave: 4 ds_read_b128 (48 cyc) + 8 VMEM loads -> 32 MFMA
// (155 cyc) => MFMA-bound (r3 config was LDS-bound at 72 cyc LDS / 39 MFMA).
// ---------------------------------------------------------------------------
__global__ void __launch_bounds__(256, 2)
gemm_tanh_d(const bf16* __restrict__ A, const bf16* __restrict__ Bp,
            const float* __restrict__ bias, bf16* __restrict__ out,
            int K, int N) {
    constexpr int BM = 128, BN = 256, MT = 4, NT = 8;
    __shared__ alignas(16) bf16 lA[2][BM * 64];   // 2 x 16 KB

    const int tid  = threadIdx.x;
    const int lane = tid & 63;
    const int w    = tid >> 6;
    const int wr   = w >> 1, wc = w & 1;
    const int quad = lane >> 4, l16 = lane & 15;
    const int brow = blockIdx.y * BM;

    // A staging: 1024 chunks (128 rows x 8), 4 per thread. LDS slot p of row r
    // holds global chunk p^(r&7) (xor swizzle -> 2-way-free frag reads).
    const bf16* gA[4];
    int lq[4];
#pragma unroll
    for (int j = 0; j < 4; ++j) {
        const int q = tid + j * 256;
        const int r = q >> 3, s = (q & 7) ^ (r & 7);
        gA[j] = A + (size_t)(brow + r) * K + s * 8;
        lq[j] = q * 8;
    }

    // B: frag base for this wave's n-columns. ntile0 = bx*16 + wc*8.
    const int kst = K >> 5;                       // k32-steps total
    const bf16* B0 = Bp + ((size_t)(blockIdx.x * 16 + wc * 8) * kst) * 512 + lane * 8;
    const size_t ntStride = (size_t)kst * 512;    // elems between n-tiles

    floatx4 acc[MT][NT];
    const floatx4 zero = {0.f, 0.f, 0.f, 0.f};
#pragma unroll
    for (int mt = 0; mt < MT; ++mt)
#pragma unroll
        for (int nt = 0; nt < NT; ++nt) acc[mt][nt] = zero;

    const int arow0 = wr * 64 + l16;
    const int x7 = l16 & 7;

    const int nIter = K / 64;
    // prologue: stage tile 0 into buf 0
#pragma unroll
    for (int j = 0; j < 4; ++j) load_lds16(gA[j], &lA[0][0] + lq[j]);

    for (int kt = 0; kt < nIter; ++kt) {
        const int cur = kt & 1;
        if (kt + 1 < nIter) {   // issue next tile into other buffer (no wait)
#pragma unroll
            for (int j = 0; j < 4; ++j)
                load_lds16(gA[j] + (kt + 1) * 64, &lA[cur ^ 1][0] + lq[j]);
            WAIT_VM(4);         // own 4 staging loads of CURRENT buf retired
        } else {
            WAIT_VM(0);
        }
        __builtin_amdgcn_s_barrier();            // publish current buffer

#pragma unroll
        for (int kk = 0; kk < 2; ++kk) {
            const int ks = kt * 2 + kk;          // global k32-step
            short8 bfr[NT];
#pragma unroll
            for (int nt = 0; nt < NT; ++nt)
                bfr[nt] = *(const short8*)(B0 + nt * ntStride + (size_t)ks * 512);
            short8 af[MT];
            const int sw = ((kk * 4 + quad) ^ x7) * 8;
#pragma unroll
            for (int mt = 0; mt < MT; ++mt)
                af[mt] = *(const short8*)(&lA[cur][0] + (arow0 + mt * 16) * 64 + sw);
#pragma unroll
            for (int mt = 0; mt < MT; ++mt)
#pragma unroll
                for (int nt = 0; nt < NT; ++nt)
                    acc[mt][nt] = __builtin_amdgcn_mfma_f32_16x16x32_bf16(
                        af[mt], bfr[nt], acc[mt][nt], 0, 0, 0);
        }
        __builtin_amdgcn_s_barrier();            // retire current buffer
    }

    const int m0 = blockIdx.y * BM + wr * 64 + quad * 4;
    const int n0 = blockIdx.x * BN + wc * 128 + l16;
#pragma unroll
    for (int mt = 0; mt < MT; ++mt)
#pragma unroll
        for (int nt = 0; nt < NT; ++nt) {
            const int n = n0 + nt * 16;
            const float b = bias[n];
#pragma unroll
            for (int i = 0; i < 4; ++i) {
                const int m = m0 + mt * 16 + i;
                out[(size_t)m * N + n] = __float2bfloat16(fast_tanh(acc[mt][nt][i] + b));
            }
        }
}

// ---------------------------------------------------------------------------
// Old LDS-staged core, kept for gemm_k only (it is memory-bound, ~its floor).
// ---------------------------------------------------------------------------
template<int BM, int BN, int WR, int WC>
__device__ __forceinline__ void gemm_core(const bf16* __restrict__ A,
                                          const bf16* __restrict__ W,
                                          int K,
                                          floatx4 (&acc)[BM / WR / 16][BN / WC / 16],
                                          bf16* lA, bf16* lB) {
    constexpr int MT = BM / WR / 16, NT = BN / WC / 16;
    constexpr int THREADS = WR * WC * 64;
    constexpr int AL = BM * 8 / THREADS;
    constexpr int BL = BN * 8 / THREADS;

    const int tid  = threadIdx.x;
    const int lane = tid & 63;
    const int w    = tid >> 6;
    const int wr   = w / WC, wc = w % WC;
    const int quad = lane >> 4, l16 = lane & 15;

    const int brow = blockIdx.y * BM;
    const int bcol = blockIdx.x * BN;

    const bf16* gA[AL]; const bf16* gW[BL];
    bf16* lAd[AL]; bf16* lBd[BL];
#pragma unroll
    for (int j = 0; j < AL; ++j) {
        const int q = tid + j * THREADS;
        const int r = q >> 3, s = (q & 7) ^ (r & 7);
        gA[j]  = A + (size_t)(brow + r) * K + s * 8;
        lAd[j] = lA + q * 8;
    }
#pragma unroll
    for (int j = 0; j < BL; ++j) {
        const int q = tid + j * THREADS;
        const int r = q >> 3, s = (q & 7) ^ (r & 7);
        gW[j]  = W + (size_t)(bcol + r) * K + s * 8;
        lBd[j] = lB + q * 8;
    }

    const floatx4 zero = {0.f, 0.f, 0.f, 0.f};
#pragma unroll
    for (int mt = 0; mt < MT; ++mt)
#pragma unroll
        for (int nt = 0; nt < NT; ++nt) acc[mt][nt] = zero;

    const int arow = wr * (BM / WR) + l16;
    const int brw  = wc * (BN / WC) + l16;
    const int x7   = l16 & 7;

    const int nIter = K / 64;
    for (int kt = 0; kt < nIter; ++kt) {
#pragma unroll
        for (int j = 0; j < AL; ++j) load_lds16(gA[j], lAd[j]);
#pragma unroll
        for (int j = 0; j < BL; ++j) load_lds16(gW[j], lBd[j]);
        __syncthreads();

#pragma unroll
        for (int kk = 0; kk < 2; ++kk) {
            const int sw = ((kk * 4 + quad) ^ x7) * 8;
            short8 af[MT], bfr[NT];
#pragma unroll
            for (int mt = 0; mt < MT; ++mt)
                af[mt] = *(const short8*)(lA + (arow + mt * 16) * 64 + sw);
#pragma unroll
            for (int nt = 0; nt < NT; ++nt)
                bfr[nt] = *(const short8*)(lB + (brw + nt * 16) * 64 + sw);
#pragma unroll
            for (int mt = 0; mt < MT; ++mt)
#pragma unroll
                for (int nt = 0; nt < NT; ++nt)
                    acc[mt][nt] = __builtin_amdgcn_mfma_f32_16x16x32_bf16(
                        af[mt], bfr[nt], acc[mt][nt], 0, 0, 0);
        }
        __syncthreads();

#pragma unroll
        for (int j = 0; j < AL; ++j) gA[j] += 64;
#pragma unroll
        for (int j = 0; j < BL; ++j) gW[j] += 64;
    }
}

// Layer-3 GEMM (N=512, K=1024) with fused RK4 logic. 64x64 tile, 4 waves.
__global__ void __launch_bounds__(256, 4)
gemm_k(const bf16* __restrict__ A, const bf16* __restrict__ W,
       const float* __restrict__ bias, int K,
       bf16* __restrict__ kacc, const float* __restrict__ h_src,
       float* __restrict__ h_out, bf16* __restrict__ x0_out,
       const float* __restrict__ temb, float alpha, float dt6, int mode) {
    constexpr int BM = 64, BN = 64, WR = 2, WC = 2;
    constexpr int MT = 2, NT = 2;
    __shared__ alignas(16) bf16 lA[BM * 64];
    __shared__ alignas(16) bf16 lB[BN * 64];
    floatx4 acc[MT][NT];
    gemm_core<BM, BN, WR, WC>(A, W, K, acc, lA, lB);

    const int tid = threadIdx.x;
    const int lane = tid & 63, w = tid >> 6;
    const int wr = w / WC, wc = w % WC;
    const int quad = lane >> 4, l16 = lane & 15;
    const int m0 = blockIdx.y * BM + wr * (BM / WR) + quad * 4;
    const int n0 = blockIdx.x * BN + wc * (BN / WC) + l16;

#pragma unroll
    for (int mt = 0; mt < MT; ++mt)
#pragma unroll
        for (int nt = 0; nt < NT; ++nt) {
            const int n = n0 + nt * 16;
            const float b = bias[n];
            const float te = temb[n];
#pragma unroll
            for (int i = 0; i < 4; ++i) {
                const int m = m0 + mt * 16 + i;
                const size_t idx = (size_t)m * 512 + n;
                const float kv = acc[mt][nt][i] + b;
                if (mode == 0) {
                    kacc[idx] = __float2bfloat16(kv);
                    x0_out[idx] = __float2bfloat16(h_src[idx] + alpha * kv + te);
                } else if (mode == 1) {
                    kacc[idx] = __float2bfloat16(__bfloat162float(kacc[idx]) + 2.f * kv);
                    x0_out[idx] = __float2bfloat16(h_src[idx] + alpha * kv + te);
                } else {
                    const float hn = h_src[idx] + dt6 * (__bfloat162float(kacc[idx]) + kv);
                    h_out[idx] = hn;
                    if (x0_out) x0_out[idx] = __float2bfloat16(hn + te);
                }
            }
        }
}

// Permute fp32 W (N,K row-major) into bf16 B-frag tiles: tile(nt,kt) holds
// 16(n)x32(k); element (n,k) at lane=(n&15)|(((k>>3)&3)<<4), byte j=k&7.
// One thread per 16 B output chunk; reads 8 contiguous fp32, writes 16 B.
__global__ void permW_kern(const float* __restrict__ W, bf16* __restrict__ out,
                           int K, int nChunks) {
    const int idx = blockIdx.x * 256 + threadIdx.x;
    if (idx >= nChunks) return;
    const int lane = idx & 63;
    const int tile = idx >> 6;
    const int kst  = K >> 5;
    const int kt = tile % kst, ntile = tile / kst;
    const int n  = ntile * 16 + (lane & 15);
    const int k0 = kt * 32 + (lane >> 4) * 8;
    const float* src = W + (size_t)n * K + k0;
    bf16* dst = out + (size_t)idx * 8;
#pragma unroll
    for (int j = 0; j < 8; ++j) dst[j] = __float2bfloat16(src[j]);
}

__global__ void f2b_kern(const float* __restrict__ src, bf16* __restrict__ dst, int n) {
    const int i = blockIdx.x * blockDim.x + threadIdx.x;
    if (i < n) dst[i] = __float2bfloat16(src[i]);
}

// temb[j][n] = (j*dt/2)*Wt[n] + bt[n], j = 0..20
__global__ void temb_kern(const float* __restrict__ Wt, const float* __restrict__ bt,
                          float* __restrict__ temb, float half_dt, int total) {
    const int i = blockIdx.x * blockDim.x + threadIdx.x;
    if (i < total) {
        const int j = i >> 9, n = i & 511;
        temb[i] = (j * half_dt) * Wt[n] + bt[n];
    }
}

__global__ void prep_kern(const float* __restrict__ h, const float* __restrict__ temb0,
                          bf16* __restrict__ x0, int total) {
    const int i = blockIdx.x * blockDim.x + threadIdx.x;
    if (i < total) x0[i] = __float2bfloat16(h[i] + temb0[i & 511]);
}

extern "C" void kernel_launch(void* const* d_in, const int* in_sizes, int n_in,
                              void* d_out, int out_size, void* d_ws, size_t ws_size,
                              hipStream_t stream) {
    const float* h_in = (const float*)d_in[0];
    const float* W1 = (const float*)d_in[1];
    const float* b1 = (const float*)d_in[2];
    const float* W2 = (const float*)d_in[3];
    const float* b2 = (const float*)d_in[4];
    const float* W3 = (const float*)d_in[5];
    const float* b3 = (const float*)d_in[6];
    const float* Wt = (const float*)d_in[7];
    const float* bt = (const float*)d_in[8];
    // n_steps (d_in[9]) is a fixed Python scalar = 10.
    const int B = 8192, H = 512, H2 = 1024, NS = 10;
    const float dt = 1.f / NS;

    char* ws = (char*)d_ws;
    auto alloc = [&](size_t bytes) {
        char* p = ws;
        ws += (bytes + 255) & ~(size_t)255;
        return p;
    };
    bf16* W1p = (bf16*)alloc((size_t)H2 * H * 2);    // permuted (B-frag order)
    bf16* W2p = (bf16*)alloc((size_t)H2 * H2 * 2);   // permuted
    bf16* W3b = (bf16*)alloc((size_t)H * H2 * 2);    // plain row-major bf16
    bf16* x0b = (bf16*)alloc((size_t)B * H * 2);
    bf16* x1b = (bf16*)alloc((size_t)B * H2 * 2);
    bf16* x2b = (bf16*)alloc((size_t)B * H2 * 2);
    bf16* kacc = (bf16*)alloc((size_t)B * H * 2);
    float* temb = (float*)alloc((size_t)21 * H * 4);
    float* hbuf = (float*)d_out;  // h ping-pongs through d_out (fp32)

    {
        int c = H2 * H / 8;   // W1: N=1024, K=512
        permW_kern<<<(c + 255) / 256, 256, 0, stream>>>(W1, W1p, H, c);
        c = H2 * H2 / 8;      // W2: N=1024, K=1024
        permW_kern<<<(c + 255) / 256, 256, 0, stream>>>(W2, W2p, H2, c);
        int n = H * H2;       // W3 plain
        f2b_kern<<<(n + 255) / 256, 256, 0, stream>>>(W3, W3b, n);
    }
    {
        const int total = 21 * H;
        temb_kern<<<(total + 255) / 256, 256, 0, stream>>>(Wt, bt, temb, dt * 0.5f, total);
    }
    {
        const int total = B * H;
        prep_kern<<<(total + 255) / 256, 256, 0, stream>>>(h_in, temb, x0b, total);
    }

    const dim3 blk256(256);
    const dim3 g1(H2 / 256, B / 128);  // 4 x 64 = 256 blocks
    const dim3 g2(H2 / 256, B / 128);  // 4 x 64 = 256 blocks
    const dim3 g3(H / 64, B / 64);     // 8 x 128 = 1024 blocks

    for (int s = 0; s < NS; ++s) {
        const float* hs = (s == 0) ? h_in : hbuf;
        const float* tmid = temb + (size_t)(2 * s + 1) * H;
        const float* tend = temb + (size_t)(2 * s + 2) * H;
        for (int e = 0; e < 4; ++e) {
            gemm_tanh_d<<<g1, blk256, 0, stream>>>(x0b, W1p, b1, x1b, H, H2);
            gemm_tanh_d<<<g2, blk256, 0, stream>>>(x1b, W2p, b2, x2b, H2, H2);
            if (e == 0)
                gemm_k<<<g3, blk256, 0, stream>>>(x2b, W3b, b3, H2, kacc, hs, nullptr,
                                                  x0b, tmid, dt * 0.5f, 0.f, 0);
            else if (e == 1)
                gemm_k<<<g3, blk256, 0, stream>>>(x2b, W3b, b3, H2, kacc, hs, nullptr,
                                                  x0b, tmid, dt * 0.5f, 0.f, 1);
            else if (e == 2)
                gemm_k<<<g3, blk256, 0, stream>>>(x2b, W3b, b3, H2, kacc, hs, nullptr,
                                                  x0b, tend, dt, 0.f, 1);
            else
                gemm_k<<<g3, blk256, 0, stream>>>(x2b, W3b, b3, H2, kacc, hs, hbuf,
                                                  (s == NS - 1) ? nullptr : x0b,
                                                  tend, 0.f, dt / 6.f, 2);
        }
    }
}

// Round 5
// 3058.902 us; speedup vs baseline: 1.1303x; 1.1303x over previous
//
#include <hip/hip_runtime.h>
#include <hip/hip_bf16.h>
#include <math.h>
#include <stdint.h>

using bf16 = __hip_bfloat16;
typedef __attribute__((ext_vector_type(8))) short short8;   // 8 bf16 = 4 VGPRs (MFMA A/B frag)
typedef __attribute__((ext_vector_type(4))) float floatx4;  // MFMA C/D frag

typedef const __attribute__((address_space(1))) void* gptr_t;
typedef __attribute__((address_space(3))) void* lptr_t;

// async global->LDS, 16B per lane. LDS dest = wave-uniform base + lane*16.
__device__ __forceinline__ void load_lds16(const bf16* g, bf16* l) {
    __builtin_amdgcn_global_load_lds((gptr_t)(uintptr_t)(const void*)g,
                                     (lptr_t)(uintptr_t)(void*)l, 16, 0, 0);
}

// wait until at most N vector-memory ops outstanding (lgkm/exp untouched)
#define WAIT_VM(n) __builtin_amdgcn_s_waitcnt(0x0F70 | (n))

// tanh(x) = 1 - 2/(exp(2x)+1); saturates correctly at +-inf; err << bf16 ulp.
__device__ __forceinline__ float fast_tanh(float x) {
    float e = __expf(2.f * x);
    return 1.f - 2.f / (e + 1.f);
}

// ---------------------------------------------------------------------------
// Layers 1 & 2: C = tanh(A·W^T + b), A (M,K) bf16 row-major, W (N,K) bf16
// row-major. Both staged through LDS (B^T layout => identical staging).
// Block 128x256, 4 waves (2m x 2n), wave tile 64x128 (MT=4, NT=8).
// Rationale (r4 post-mortem): the structure is CU-level LDS-BW-bound and LDS
// traffic per k-step scales with (wave_m + wave_n) only -> maximize wave tile.
// Per-CU per k32: LDS = 4 waves x 12 KB reads + 24 KB staging = 72 KB
// (~400 cyc @ ~180 B/cyc) vs MFMA 310 cyc/SIMD -> near-balanced (r3 was 3.5x
// LDS-bound). Double-buffered LDS (2 x 48 KB) with manual fine-grained
// vmcnt: staging loads are the ONLY VMEM ops in the K-loop, so WAIT_VM(12)
// is exact (r4's flaw was B-frag VMEM loads polluting the vmcnt queue AND
// unreused L2 traffic of 32 KB/CU/k-step vs ~56 B/cyc per-CU L2 BW).
// XOR-8 chunk swizzle: LDS slot p of row r holds global chunk p^(r&7) ->
// fragment ds_read_b128 are 2-way bank-aliased (free, m136).
// ---------------------------------------------------------------------------
__global__ void __launch_bounds__(256, 1)
gemm_tanh2(const bf16* __restrict__ A, const bf16* __restrict__ W,
           const float* __restrict__ bias, bf16* __restrict__ out,
           int K, int N) {
    constexpr int BM = 128, BN = 256, MT = 4, NT = 8;
    constexpr int AL = 4, BL = 8;                  // staging chunks per thread
    __shared__ alignas(16) bf16 lA[2][BM * 64];    // 2 x 16 KB
    __shared__ alignas(16) bf16 lB[2][BN * 64];    // 2 x 32 KB

    const int tid  = threadIdx.x;
    const int lane = tid & 63;
    const int w    = tid >> 6;
    const int wr   = w >> 1, wc = w & 1;
    const int quad = lane >> 4, l16 = lane & 15;
    const int brow = blockIdx.y * BM;
    const int bcol = blockIdx.x * BN;

    const bf16* gA[AL]; int lqA[AL];
#pragma unroll
    for (int j = 0; j < AL; ++j) {
        const int q = tid + j * 256;
        const int r = q >> 3, s = (q & 7) ^ (r & 7);
        gA[j]  = A + (size_t)(brow + r) * K + s * 8;
        lqA[j] = q * 8;
    }
    const bf16* gW[BL]; int lqB[BL];
#pragma unroll
    for (int j = 0; j < BL; ++j) {
        const int q = tid + j * 256;
        const int r = q >> 3, s = (q & 7) ^ (r & 7);
        gW[j]  = W + (size_t)(bcol + r) * K + s * 8;
        lqB[j] = q * 8;
    }

    floatx4 acc[MT][NT];
    const floatx4 zero = {0.f, 0.f, 0.f, 0.f};
#pragma unroll
    for (int mt = 0; mt < MT; ++mt)
#pragma unroll
        for (int nt = 0; nt < NT; ++nt) acc[mt][nt] = zero;

    const int arow0 = wr * 64 + l16;
    const int brow0 = wc * 128 + l16;
    const int x7 = l16 & 7;

    const int nIter = K / 64;
    // prologue: stage tile 0 into buffer 0 (12 loads/thread)
#pragma unroll
    for (int j = 0; j < AL; ++j) load_lds16(gA[j], &lA[0][0] + lqA[j]);
#pragma unroll
    for (int j = 0; j < BL; ++j) load_lds16(gW[j], &lB[0][0] + lqB[j]);

    for (int kt = 0; kt < nIter; ++kt) {
        const int cur = kt & 1;
        if (kt + 1 < nIter) {
            // issue next tile into other buffer (its compute finished at the
            // trailing barrier of iteration kt-1), then wait for OUR tile:
            // after issue, <=24 outstanding; oldest 12 are current buffer.
#pragma unroll
            for (int j = 0; j < AL; ++j)
                load_lds16(gA[j] + (kt + 1) * 64, &lA[cur ^ 1][0] + lqA[j]);
#pragma unroll
            for (int j = 0; j < BL; ++j)
                load_lds16(gW[j] + (kt + 1) * 64, &lB[cur ^ 1][0] + lqB[j]);
            WAIT_VM(12);
        } else {
            WAIT_VM(0);
        }
        __builtin_amdgcn_s_barrier();              // publish current buffer

#pragma unroll
        for (int kk = 0; kk < 2; ++kk) {
            const int sw = ((kk * 4 + quad) ^ x7) * 8;
            short8 af[MT], bfr[NT];
#pragma unroll
            for (int mt = 0; mt < MT; ++mt)
                af[mt] = *(const short8*)(&lA[cur][0] + (arow0 + mt * 16) * 64 + sw);
#pragma unroll
            for (int nt = 0; nt < NT; ++nt)
                bfr[nt] = *(const short8*)(&lB[cur][0] + (brow0 + nt * 16) * 64 + sw);
#pragma unroll
            for (int mt = 0; mt < MT; ++mt)
#pragma unroll
                for (int nt = 0; nt < NT; ++nt)
                    acc[mt][nt] = __builtin_amdgcn_mfma_f32_16x16x32_bf16(
                        af[mt], bfr[nt], acc[mt][nt], 0, 0, 0);
        }
        __builtin_amdgcn_s_barrier();              // retire current buffer
    }

    const int m0 = blockIdx.y * BM + wr * 64 + quad * 4;
    const int n0 = blockIdx.x * BN + wc * 128 + l16;
#pragma unroll
    for (int mt = 0; mt < MT; ++mt)
#pragma unroll
        for (int nt = 0; nt < NT; ++nt) {
            const int n = n0 + nt * 16;
            const float b = bias[n];
#pragma unroll
            for (int i = 0; i < 4; ++i) {
                const int m = m0 + mt * 16 + i;
                out[(size_t)m * N + n] = __float2bfloat16(fast_tanh(acc[mt][nt][i] + b));
            }
        }
}

// ---------------------------------------------------------------------------
// LDS-staged 2-barrier core for gemm_k (memory-bound, ~its floor).
// ---------------------------------------------------------------------------
template<int BM, int BN, int WR, int WC>
__device__ __forceinline__ void gemm_core(const bf16* __restrict__ A,
                                          const bf16* __restrict__ W,
                                          int K,
                                          floatx4 (&acc)[BM / WR / 16][BN / WC / 16],
                                          bf16* lA, bf16* lB) {
    constexpr int MT = BM / WR / 16, NT = BN / WC / 16;
    constexpr int THREADS = WR * WC * 64;
    constexpr int AL = BM * 8 / THREADS;
    constexpr int BL = BN * 8 / THREADS;

    const int tid  = threadIdx.x;
    const int lane = tid & 63;
    const int w    = tid >> 6;
    const int wr   = w / WC, wc = w % WC;
    const int quad = lane >> 4, l16 = lane & 15;

    const int brow = blockIdx.y * BM;
    const int bcol = blockIdx.x * BN;

    const bf16* gA[AL]; const bf16* gW[BL];
    bf16* lAd[AL]; bf16* lBd[BL];
#pragma unroll
    for (int j = 0; j < AL; ++j) {
        const int q = tid + j * THREADS;
        const int r = q >> 3, s = (q & 7) ^ (r & 7);
        gA[j]  = A + (size_t)(brow + r) * K + s * 8;
        lAd[j] = lA + q * 8;
    }
#pragma unroll
    for (int j = 0; j < BL; ++j) {
        const int q = tid + j * THREADS;
        const int r = q >> 3, s = (q & 7) ^ (r & 7);
        gW[j]  = W + (size_t)(bcol + r) * K + s * 8;
        lBd[j] = lB + q * 8;
    }

    const floatx4 zero = {0.f, 0.f, 0.f, 0.f};
#pragma unroll
    for (int mt = 0; mt < MT; ++mt)
#pragma unroll
        for (int nt = 0; nt < NT; ++nt) acc[mt][nt] = zero;

    const int arow = wr * (BM / WR) + l16;
    const int brw  = wc * (BN / WC) + l16;
    const int x7   = l16 & 7;

    const int nIter = K / 64;
    for (int kt = 0; kt < nIter; ++kt) {
#pragma unroll
        for (int j = 0; j < AL; ++j) load_lds16(gA[j], lAd[j]);
#pragma unroll
        for (int j = 0; j < BL; ++j) load_lds16(gW[j], lBd[j]);
        __syncthreads();

#pragma unroll
        for (int kk = 0; kk < 2; ++kk) {
            const int sw = ((kk * 4 + quad) ^ x7) * 8;
            short8 af[MT], bfr[NT];
#pragma unroll
            for (int mt = 0; mt < MT; ++mt)
                af[mt] = *(const short8*)(lA + (arow + mt * 16) * 64 + sw);
#pragma unroll
            for (int nt = 0; nt < NT; ++nt)
                bfr[nt] = *(const short8*)(lB + (brw + nt * 16) * 64 + sw);
#pragma unroll
            for (int mt = 0; mt < MT; ++mt)
#pragma unroll
                for (int nt = 0; nt < NT; ++nt)
                    acc[mt][nt] = __builtin_amdgcn_mfma_f32_16x16x32_bf16(
                        af[mt], bfr[nt], acc[mt][nt], 0, 0, 0);
        }
        __syncthreads();

#pragma unroll
        for (int j = 0; j < AL; ++j) gA[j] += 64;
#pragma unroll
        for (int j = 0; j < BL; ++j) gW[j] += 64;
    }
}

// Layer-3 GEMM (N=512, K=1024) with fused RK4 logic. 64x64 tile, 4 waves.
// kv = acc + b3[n]
// mode 0 (k1):   kacc = kv;        x0 = bf16(h + alpha*kv + temb)
// mode 1 (k2/3): kacc += 2*kv;     x0 = bf16(h + alpha*kv + temb)
// mode 2 (k4):   hn = h + dt6*(kacc + kv); h_out = hn; if (x0_out) x0 = bf16(hn + temb)
__global__ void __launch_bounds__(256, 4)
gemm_k(const bf16* __restrict__ A, const bf16* __restrict__ W,
       const float* __restrict__ bias, int K,
       bf16* __restrict__ kacc, const float* __restrict__ h_src,
       float* __restrict__ h_out, bf16* __restrict__ x0_out,
       const float* __restrict__ temb, float alpha, float dt6, int mode) {
    constexpr int BM = 64, BN = 64, WR = 2, WC = 2;
    constexpr int MT = 2, NT = 2;
    __shared__ alignas(16) bf16 lA[BM * 64];
    __shared__ alignas(16) bf16 lB[BN * 64];
    floatx4 acc[MT][NT];
    gemm_core<BM, BN, WR, WC>(A, W, K, acc, lA, lB);

    const int tid = threadIdx.x;
    const int lane = tid & 63, w = tid >> 6;
    const int wr = w / WC, wc = w % WC;
    const int quad = lane >> 4, l16 = lane & 15;
    const int m0 = blockIdx.y * BM + wr * (BM / WR) + quad * 4;
    const int n0 = blockIdx.x * BN + wc * (BN / WC) + l16;

#pragma unroll
    for (int mt = 0; mt < MT; ++mt)
#pragma unroll
        for (int nt = 0; nt < NT; ++nt) {
            const int n = n0 + nt * 16;
            const float b = bias[n];
            const float te = temb[n];
#pragma unroll
            for (int i = 0; i < 4; ++i) {
                const int m = m0 + mt * 16 + i;
                const size_t idx = (size_t)m * 512 + n;
                const float kv = acc[mt][nt][i] + b;
                if (mode == 0) {
                    kacc[idx] = __float2bfloat16(kv);
                    x0_out[idx] = __float2bfloat16(h_src[idx] + alpha * kv + te);
                } else if (mode == 1) {
                    kacc[idx] = __float2bfloat16(__bfloat162float(kacc[idx]) + 2.f * kv);
                    x0_out[idx] = __float2bfloat16(h_src[idx] + alpha * kv + te);
                } else {
                    const float hn = h_src[idx] + dt6 * (__bfloat162float(kacc[idx]) + kv);
                    h_out[idx] = hn;
                    if (x0_out) x0_out[idx] = __float2bfloat16(hn + te);
                }
            }
        }
}

__global__ void f2b_kern(const float* __restrict__ src, bf16* __restrict__ dst, int n) {
    const int i = blockIdx.x * blockDim.x + threadIdx.x;
    if (i < n) dst[i] = __float2bfloat16(src[i]);
}

// temb[j][n] = (j*dt/2)*Wt[n] + bt[n], j = 0..20
__global__ void temb_kern(const float* __restrict__ Wt, const float* __restrict__ bt,
                          float* __restrict__ temb, float half_dt, int total) {
    const int i = blockIdx.x * blockDim.x + threadIdx.x;
    if (i < total) {
        const int j = i >> 9, n = i & 511;
        temb[i] = (j * half_dt) * Wt[n] + bt[n];
    }
}

__global__ void prep_kern(const float* __restrict__ h, const float* __restrict__ temb0,
                          bf16* __restrict__ x0, int total) {
    const int i = blockIdx.x * blockDim.x + threadIdx.x;
    if (i < total) x0[i] = __float2bfloat16(h[i] + temb0[i & 511]);
}

extern "C" void kernel_launch(void* const* d_in, const int* in_sizes, int n_in,
                              void* d_out, int out_size, void* d_ws, size_t ws_size,
                              hipStream_t stream) {
    const float* h_in = (const float*)d_in[0];
    const float* W1 = (const float*)d_in[1];
    const float* b1 = (const float*)d_in[2];
    const float* W2 = (const float*)d_in[3];
    const float* b2 = (const float*)d_in[4];
    const float* W3 = (const float*)d_in[5];
    const float* b3 = (const float*)d_in[6];
    const float* Wt = (const float*)d_in[7];
    const float* bt = (const float*)d_in[8];
    // n_steps (d_in[9]) is a fixed Python scalar = 10.
    const int B = 8192, H = 512, H2 = 1024, NS = 10;
    const float dt = 1.f / NS;

    char* ws = (char*)d_ws;
    auto alloc = [&](size_t bytes) {
        char* p = ws;
        ws += (bytes + 255) & ~(size_t)255;
        return p;
    };
    bf16* W1b = (bf16*)alloc((size_t)H2 * H * 2);
    bf16* W2b = (bf16*)alloc((size_t)H2 * H2 * 2);
    bf16* W3b = (bf16*)alloc((size_t)H * H2 * 2);
    bf16* x0b = (bf16*)alloc((size_t)B * H * 2);
    bf16* x1b = (bf16*)alloc((size_t)B * H2 * 2);
    bf16* x2b = (bf16*)alloc((size_t)B * H2 * 2);
    bf16* kacc = (bf16*)alloc((size_t)B * H * 2);
    float* temb = (float*)alloc((size_t)21 * H * 4);
    float* hbuf = (float*)d_out;  // h ping-pongs through d_out (fp32)

    {
        int n = H2 * H;
        f2b_kern<<<(n + 255) / 256, 256, 0, stream>>>(W1, W1b, n);
        n = H2 * H2;
        f2b_kern<<<(n + 255) / 256, 256, 0, stream>>>(W2, W2b, n);
        n = H * H2;
        f2b_kern<<<(n + 255) / 256, 256, 0, stream>>>(W3, W3b, n);
    }
    {
        const int total = 21 * H;
        temb_kern<<<(total + 255) / 256, 256, 0, stream>>>(Wt, bt, temb, dt * 0.5f, total);
    }
    {
        const int total = B * H;
        prep_kern<<<(total + 255) / 256, 256, 0, stream>>>(h_in, temb, x0b, total);
    }

    const dim3 blk256(256);
    const dim3 g1(H2 / 256, B / 128);  // 4 x 64 = 256 blocks (1/CU)
    const dim3 g2(H2 / 256, B / 128);  // 4 x 64 = 256 blocks
    const dim3 g3(H / 64, B / 64);     // 8 x 128 = 1024 blocks

    for (int s = 0; s < NS; ++s) {
        const float* hs = (s == 0) ? h_in : hbuf;
        const float* tmid = temb + (size_t)(2 * s + 1) * H;
        const float* tend = temb + (size_t)(2 * s + 2) * H;
        for (int e = 0; e < 4; ++e) {
            gemm_tanh2<<<g1, blk256, 0, stream>>>(x0b, W1b, b1, x1b, H, H2);
            gemm_tanh2<<<g2, blk256, 0, stream>>>(x1b, W2b, b2, x2b, H2, H2);
            if (e == 0)
                gemm_k<<<g3, blk256, 0, stream>>>(x2b, W3b, b3, H2, kacc, hs, nullptr,
                                                  x0b, tmid, dt * 0.5f, 0.f, 0);
            else if (e == 1)
                gemm_k<<<g3, blk256, 0, stream>>>(x2b, W3b, b3, H2, kacc, hs, nullptr,
                                                  x0b, tmid, dt * 0.5f, 0.f, 1);
            else if (e == 2)
                gemm_k<<<g3, blk256, 0, stream>>>(x2b, W3b, b3, H2, kacc, hs, nullptr,
                                                  x0b, tend, dt, 0.f, 1);
            else
                gemm_k<<<g3, blk256, 0, stream>>>(x2b, W3b, b3, H2, kacc, hs, hbuf,
                                                  (s == NS - 1) ? nullptr : x0b,
                                                  tend, 0.f, dt / 6.f, 2);
        }
    }
}

// Round 6
// 2783.926 us; speedup vs baseline: 1.2420x; 1.0988x over previous
//
#include <hip/hip_runtime.h>
#include <hip/hip_bf16.h>
#include <math.h>
#include <stdint.h>

using bf16 = __hip_bfloat16;
typedef __attribute__((ext_vector_type(8))) short short8;   // 8 bf16 = 4 VGPRs (MFMA A/B frag)
typedef __attribute__((ext_vector_type(4))) float floatx4;  // MFMA C/D frag

typedef const __attribute__((address_space(1))) void* gptr_t;
typedef __attribute__((address_space(3))) void* lptr_t;

// async global->LDS, 16B per lane. LDS dest = wave-uniform base + lane*16.
__device__ __forceinline__ void load_lds16(const bf16* g, bf16* l) {
    __builtin_amdgcn_global_load_lds((gptr_t)(uintptr_t)(const void*)g,
                                     (lptr_t)(uintptr_t)(void*)l, 16, 0, 0);
}

// wait until at most N vector-memory ops outstanding. gfx9 vmcnt is 6 bits
// split lo[3:0]=bits3:0, hi[5:4]=bits15:14; lgkm/exp left at max (no wait).
#define WAIT_VM(n) __builtin_amdgcn_s_waitcnt(0x0F70 | ((n) & 15) | (((n) >> 4) << 14))

// tanh(x) = 1 - 2/(exp(2x)+1); saturates correctly at +-inf; err << bf16 ulp.
__device__ __forceinline__ float fast_tanh(float x) {
    float e = __expf(2.f * x);
    return 1.f - 2.f / (e + 1.f);
}

// ---------------------------------------------------------------------------
// Layers 1 & 2: C = tanh(A·W^T + b). Block 128x256, 4 waves, wave tile 64x128
// (the only wave tile clearing the 128 B/cyc LDS pipe: wm*wn/(wm+wn)=42.7
// FLOP/B vs required ~26). TRIPLE-buffered LDS (3 x 48 KB = 144 KB): 2-deep
// prefetch (~1120 cyc in flight) covers HBM-miss latency (~900 cyc) that
// r5's 1-deep dbuf (~560 cyc) could not — at 1 blk/CU there are no other
// waves to hide the shortfall. XCD swizzle: the 4 blocks sharing an A-row
// stripe land on one XCD -> A re-reads hit local L2 (~200 cyc) not HBM.
// XOR-8 chunk swizzle keeps frag ds_read_b128 at free 2-way bank aliasing.
// ---------------------------------------------------------------------------
__global__ void __launch_bounds__(256, 1)
gemm_tanh3(const bf16* __restrict__ A, const bf16* __restrict__ W,
           const float* __restrict__ bias, bf16* __restrict__ out,
           int K, int N) {
    constexpr int BM = 128, BN = 256, MT = 4, NT = 8;
    constexpr int AL = 4, BL = 8;                   // staging chunks per thread
    __shared__ alignas(16) bf16 lA[3][BM * 64];     // 3 x 16 KB
    __shared__ alignas(16) bf16 lB[3][BN * 64];     // 3 x 32 KB

    // XCD swizzle: hw assigns block b to XCD b&7. Put the gridDim.x(=4)
    // n-tiles of one m-stripe on the same XCD.
    const int b   = blockIdx.x + gridDim.x * blockIdx.y;
    const int xcd = b & 7, j = b >> 3;
    const int bx  = j & 3;                 // n-tile 0..3
    const int by  = xcd + 8 * (j >> 2);    // m-tile 0..63

    const int tid  = threadIdx.x;
    const int lane = tid & 63;
    const int w    = tid >> 6;
    const int wr   = w >> 1, wc = w & 1;
    const int quad = lane >> 4, l16 = lane & 15;
    const int brow = by * BM;
    const int bcol = bx * BN;

    const bf16* gA[AL]; int lqA[AL];
#pragma unroll
    for (int jj = 0; jj < AL; ++jj) {
        const int q = tid + jj * 256;
        const int r = q >> 3, s = (q & 7) ^ (r & 7);
        gA[jj]  = A + (size_t)(brow + r) * K + s * 8;
        lqA[jj] = q * 8;
    }
    const bf16* gW[BL]; int lqB[BL];
#pragma unroll
    for (int jj = 0; jj < BL; ++jj) {
        const int q = tid + jj * 256;
        const int r = q >> 3, s = (q & 7) ^ (r & 7);
        gW[jj]  = W + (size_t)(bcol + r) * K + s * 8;
        lqB[jj] = q * 8;
    }

    floatx4 acc[MT][NT];
    const floatx4 zero = {0.f, 0.f, 0.f, 0.f};
#pragma unroll
    for (int mt = 0; mt < MT; ++mt)
#pragma unroll
        for (int nt = 0; nt < NT; ++nt) acc[mt][nt] = zero;

    const int arow0 = wr * 64 + l16;
    const int brow0 = wc * 128 + l16;
    const int x7 = l16 & 7;

    const int nIter = K / 64;   // 8 (K=512) or 16 (K=1024) — always >= 3
    // prologue: stage tiles 0 and 1 (12 loads/thread each)
#pragma unroll
    for (int jj = 0; jj < AL; ++jj) load_lds16(gA[jj], &lA[0][0] + lqA[jj]);
#pragma unroll
    for (int jj = 0; jj < BL; ++jj) load_lds16(gW[jj], &lB[0][0] + lqB[jj]);
#pragma unroll
    for (int jj = 0; jj < AL; ++jj) load_lds16(gA[jj] + 64, &lA[1][0] + lqA[jj]);
#pragma unroll
    for (int jj = 0; jj < BL; ++jj) load_lds16(gW[jj] + 64, &lB[1][0] + lqB[jj]);

    for (int kt = 0; kt < nIter; ++kt) {
        const int cur = kt % 3;
        if (kt + 2 < nIter) {
            // stage tile kt+2 into buffer (kt+2)%3 (its previous tile kt-1
            // finished compute at iteration kt-1's trailing barrier).
            const int nxt = (kt + 2) % 3;
#pragma unroll
            for (int jj = 0; jj < AL; ++jj)
                load_lds16(gA[jj] + (kt + 2) * 64, &lA[nxt][0] + lqA[jj]);
#pragma unroll
            for (int jj = 0; jj < BL; ++jj)
                load_lds16(gW[jj] + (kt + 2) * 64, &lB[nxt][0] + lqB[jj]);
            WAIT_VM(24);        // <=36 outstanding; oldest 12 (tile kt) done
        } else if (kt + 1 < nIter) {
            WAIT_VM(12);        // tiles kt,kt+1 in flight; tile kt done
        } else {
            WAIT_VM(0);
        }
        __builtin_amdgcn_s_barrier();              // publish tile kt

#pragma unroll
        for (int kk = 0; kk < 2; ++kk) {
            const int sw = ((kk * 4 + quad) ^ x7) * 8;
            short8 af[MT], bfr[NT];
#pragma unroll
            for (int mt = 0; mt < MT; ++mt)
                af[mt] = *(const short8*)(&lA[cur][0] + (arow0 + mt * 16) * 64 + sw);
#pragma unroll
            for (int nt = 0; nt < NT; ++nt)
                bfr[nt] = *(const short8*)(&lB[cur][0] + (brow0 + nt * 16) * 64 + sw);
#pragma unroll
            for (int mt = 0; mt < MT; ++mt)
#pragma unroll
                for (int nt = 0; nt < NT; ++nt)
                    acc[mt][nt] = __builtin_amdgcn_mfma_f32_16x16x32_bf16(
                        af[mt], bfr[nt], acc[mt][nt], 0, 0, 0);
        }
        __builtin_amdgcn_s_barrier();              // retire tile kt
    }

    const int m0 = brow + wr * 64 + quad * 4;
    const int n0 = bcol + wc * 128 + l16;
#pragma unroll
    for (int mt = 0; mt < MT; ++mt)
#pragma unroll
        for (int nt = 0; nt < NT; ++nt) {
            const int n = n0 + nt * 16;
            const float bb = bias[n];
#pragma unroll
            for (int i = 0; i < 4; ++i) {
                const int m = m0 + mt * 16 + i;
                out[(size_t)m * N + n] = __float2bfloat16(fast_tanh(acc[mt][nt][i] + bb));
            }
        }
}

// ---------------------------------------------------------------------------
// LDS-staged 2-barrier core for gemm_k (memory-bound, ~its floor).
// brow/bcol passed in (XCD-swizzled by caller).
// ---------------------------------------------------------------------------
template<int BM, int BN, int WR, int WC>
__device__ __forceinline__ void gemm_core(const bf16* __restrict__ A,
                                          const bf16* __restrict__ W,
                                          int K, int brow, int bcol,
                                          floatx4 (&acc)[BM / WR / 16][BN / WC / 16],
                                          bf16* lA, bf16* lB) {
    constexpr int MT = BM / WR / 16, NT = BN / WC / 16;
    constexpr int THREADS = WR * WC * 64;
    constexpr int AL = BM * 8 / THREADS;
    constexpr int BL = BN * 8 / THREADS;

    const int tid  = threadIdx.x;
    const int lane = tid & 63;
    const int w    = tid >> 6;
    const int wr   = w / WC, wc = w % WC;
    const int quad = lane >> 4, l16 = lane & 15;

    const bf16* gA[AL]; const bf16* gW[BL];
    bf16* lAd[AL]; bf16* lBd[BL];
#pragma unroll
    for (int j = 0; j < AL; ++j) {
        const int q = tid + j * THREADS;
        const int r = q >> 3, s = (q & 7) ^ (r & 7);
        gA[j]  = A + (size_t)(brow + r) * K + s * 8;
        lAd[j] = lA + q * 8;
    }
#pragma unroll
    for (int j = 0; j < BL; ++j) {
        const int q = tid + j * THREADS;
        const int r = q >> 3, s = (q & 7) ^ (r & 7);
        gW[j]  = W + (size_t)(bcol + r) * K + s * 8;
        lBd[j] = lB + q * 8;
    }

    const floatx4 zero = {0.f, 0.f, 0.f, 0.f};
#pragma unroll
    for (int mt = 0; mt < MT; ++mt)
#pragma unroll
        for (int nt = 0; nt < NT; ++nt) acc[mt][nt] = zero;

    const int arow = wr * (BM / WR) + l16;
    const int brw  = wc * (BN / WC) + l16;
    const int x7   = l16 & 7;

    const int nIter = K / 64;
    for (int kt = 0; kt < nIter; ++kt) {
#pragma unroll
        for (int j = 0; j < AL; ++j) load_lds16(gA[j], lAd[j]);
#pragma unroll
        for (int j = 0; j < BL; ++j) load_lds16(gW[j], lBd[j]);
        __syncthreads();

#pragma unroll
        for (int kk = 0; kk < 2; ++kk) {
            const int sw = ((kk * 4 + quad) ^ x7) * 8;
            short8 af[MT], bfr[NT];
#pragma unroll
            for (int mt = 0; mt < MT; ++mt)
                af[mt] = *(const short8*)(lA + (arow + mt * 16) * 64 + sw);
#pragma unroll
            for (int nt = 0; nt < NT; ++nt)
                bfr[nt] = *(const short8*)(lB + (brw + nt * 16) * 64 + sw);
#pragma unroll
            for (int mt = 0; mt < MT; ++mt)
#pragma unroll
                for (int nt = 0; nt < NT; ++nt)
                    acc[mt][nt] = __builtin_amdgcn_mfma_f32_16x16x32_bf16(
                        af[mt], bfr[nt], acc[mt][nt], 0, 0, 0);
        }
        __syncthreads();

#pragma unroll
        for (int j = 0; j < AL; ++j) gA[j] += 64;
#pragma unroll
        for (int j = 0; j < BL; ++j) gW[j] += 64;
    }
}

// Layer-3 GEMM (N=512, K=1024) with fused RK4 logic. 64x64 tile, 4 waves.
// kv = acc + b3[n]
// mode 0 (k1):   kacc = kv;        x0 = bf16(h + alpha*kv + temb)
// mode 1 (k2/3): kacc += 2*kv;     x0 = bf16(h + alpha*kv + temb)
// mode 2 (k4):   hn = h + dt6*(kacc + kv); h_out = hn; if (x0_out) x0 = bf16(hn + temb)
__global__ void __launch_bounds__(256, 4)
gemm_k(const bf16* __restrict__ A, const bf16* __restrict__ W,
       const float* __restrict__ bias, int K,
       bf16* __restrict__ kacc, const float* __restrict__ h_src,
       float* __restrict__ h_out, bf16* __restrict__ x0_out,
       const float* __restrict__ temb, float alpha, float dt6, int mode) {
    constexpr int BM = 64, BN = 64, WR = 2, WC = 2;
    constexpr int MT = 2, NT = 2;
    __shared__ alignas(16) bf16 lA[BM * 64];
    __shared__ alignas(16) bf16 lB[BN * 64];

    // XCD swizzle: the 8 n-tiles sharing an A-row stripe -> one XCD.
    const int b   = blockIdx.x + gridDim.x * blockIdx.y;   // grid (8,128)
    const int xcd = b & 7, j = b >> 3;                     // j in [0,128)
    const int bx  = j & 7;                                 // n-tile 0..7
    const int by  = xcd + 8 * (j >> 3);                    // m-tile 0..127

    floatx4 acc[MT][NT];
    gemm_core<BM, BN, WR, WC>(A, W, K, by * BM, bx * BN, acc, lA, lB);

    const int tid = threadIdx.x;
    const int lane = tid & 63, w = tid >> 6;
    const int wr = w / WC, wc = w % WC;
    const int quad = lane >> 4, l16 = lane & 15;
    const int m0 = by * BM + wr * (BM / WR) + quad * 4;
    const int n0 = bx * BN + wc * (BN / WC) + l16;

#pragma unroll
    for (int mt = 0; mt < MT; ++mt)
#pragma unroll
        for (int nt = 0; nt < NT; ++nt) {
            const int n = n0 + nt * 16;
            const float bb = bias[n];
            const float te = temb[n];
#pragma unroll
            for (int i = 0; i < 4; ++i) {
                const int m = m0 + mt * 16 + i;
                const size_t idx = (size_t)m * 512 + n;
                const float kv = acc[mt][nt][i] + bb;
                if (mode == 0) {
                    kacc[idx] = __float2bfloat16(kv);
                    x0_out[idx] = __float2bfloat16(h_src[idx] + alpha * kv + te);
                } else if (mode == 1) {
                    kacc[idx] = __float2bfloat16(__bfloat162float(kacc[idx]) + 2.f * kv);
                    x0_out[idx] = __float2bfloat16(h_src[idx] + alpha * kv + te);
                } else {
                    const float hn = h_src[idx] + dt6 * (__bfloat162float(kacc[idx]) + kv);
                    h_out[idx] = hn;
                    if (x0_out) x0_out[idx] = __float2bfloat16(hn + te);
                }
            }
        }
}

__global__ void f2b_kern(const float* __restrict__ src, bf16* __restrict__ dst, int n) {
    const int i = blockIdx.x * blockDim.x + threadIdx.x;
    if (i < n) dst[i] = __float2bfloat16(src[i]);
}

// temb[j][n] = (j*dt/2)*Wt[n] + bt[n], j = 0..20
__global__ void temb_kern(const float* __restrict__ Wt, const float* __restrict__ bt,
                          float* __restrict__ temb, float half_dt, int total) {
    const int i = blockIdx.x * blockDim.x + threadIdx.x;
    if (i < total) {
        const int j = i >> 9, n = i & 511;
        temb[i] = (j * half_dt) * Wt[n] + bt[n];
    }
}

__global__ void prep_kern(const float* __restrict__ h, const float* __restrict__ temb0,
                          bf16* __restrict__ x0, int total) {
    const int i = blockIdx.x * blockDim.x + threadIdx.x;
    if (i < total) x0[i] = __float2bfloat16(h[i] + temb0[i & 511]);
}

extern "C" void kernel_launch(void* const* d_in, const int* in_sizes, int n_in,
                              void* d_out, int out_size, void* d_ws, size_t ws_size,
                              hipStream_t stream) {
    const float* h_in = (const float*)d_in[0];
    const float* W1 = (const float*)d_in[1];
    const float* b1 = (const float*)d_in[2];
    const float* W2 = (const float*)d_in[3];
    const float* b2 = (const float*)d_in[4];
    const float* W3 = (const float*)d_in[5];
    const float* b3 = (const float*)d_in[6];
    const float* Wt = (const float*)d_in[7];
    const float* bt = (const float*)d_in[8];
    // n_steps (d_in[9]) is a fixed Python scalar = 10.
    const int B = 8192, H = 512, H2 = 1024, NS = 10;
    const float dt = 1.f / NS;

    char* ws = (char*)d_ws;
    auto alloc = [&](size_t bytes) {
        char* p = ws;
        ws += (bytes + 255) & ~(size_t)255;
        return p;
    };
    bf16* W1b = (bf16*)alloc((size_t)H2 * H * 2);
    bf16* W2b = (bf16*)alloc((size_t)H2 * H2 * 2);
    bf16* W3b = (bf16*)alloc((size_t)H * H2 * 2);
    bf16* x0b = (bf16*)alloc((size_t)B * H * 2);
    bf16* x1b = (bf16*)alloc((size_t)B * H2 * 2);
    bf16* x2b = (bf16*)alloc((size_t)B * H2 * 2);
    bf16* kacc = (bf16*)alloc((size_t)B * H * 2);
    float* temb = (float*)alloc((size_t)21 * H * 4);
    float* hbuf = (float*)d_out;  // h ping-pongs through d_out (fp32)

    {
        int n = H2 * H;
        f2b_kern<<<(n + 255) / 256, 256, 0, stream>>>(W1, W1b, n);
        n = H2 * H2;
        f2b_kern<<<(n + 255) / 256, 256, 0, stream>>>(W2, W2b, n);
        n = H * H2;
        f2b_kern<<<(n + 255) / 256, 256, 0, stream>>>(W3, W3b, n);
    }
    {
        const int total = 21 * H;
        temb_kern<<<(total + 255) / 256, 256, 0, stream>>>(Wt, bt, temb, dt * 0.5f, total);
    }
    {
        const int total = B * H;
        prep_kern<<<(total + 255) / 256, 256, 0, stream>>>(h_in, temb, x0b, total);
    }

    const dim3 blk256(256);
    const dim3 g1(H2 / 256, B / 128);  // 4 x 64 = 256 blocks (1/CU)
    const dim3 g2(H2 / 256, B / 128);  // 4 x 64 = 256 blocks
    const dim3 g3(H / 64, B / 64);     // 8 x 128 = 1024 blocks

    for (int s = 0; s < NS; ++s) {
        const float* hs = (s == 0) ? h_in : hbuf;
        const float* tmid = temb + (size_t)(2 * s + 1) * H;
        const float* tend = temb + (size_t)(2 * s + 2) * H;
        for (int e = 0; e < 4; ++e) {
            gemm_tanh3<<<g1, blk256, 0, stream>>>(x0b, W1b, b1, x1b, H, H2);
            gemm_tanh3<<<g2, blk256, 0, stream>>>(x1b, W2b, b2, x2b, H2, H2);
            if (e == 0)
                gemm_k<<<g3, blk256, 0, stream>>>(x2b, W3b, b3, H2, kacc, hs, nullptr,
                                                  x0b, tmid, dt * 0.5f, 0.f, 0);
            else if (e == 1)
                gemm_k<<<g3, blk256, 0, stream>>>(x2b, W3b, b3, H2, kacc, hs, nullptr,
                                                  x0b, tmid, dt * 0.5f, 0.f, 1);
            else if (e == 2)
                gemm_k<<<g3, blk256, 0, stream>>>(x2b, W3b, b3, H2, kacc, hs, nullptr,
                                                  x0b, tend, dt, 0.f, 1);
            else
                gemm_k<<<g3, blk256, 0, stream>>>(x2b, W3b, b3, H2, kacc, hs, hbuf,
                                                  (s == NS - 1) ? nullptr : x0b,
                                                  tend, 0.f, dt / 6.f, 2);
        }
    }
}

// Round 7
// 2426.530 us; speedup vs baseline: 1.4249x; 1.1473x over previous
//
#include <hip/hip_runtime.h>
#include <hip/hip_bf16.h>
#include <math.h>
#include <stdint.h>

using bf16 = __hip_bfloat16;
typedef __attribute__((ext_vector_type(8))) short short8;   // 8 bf16 = 4 VGPRs (MFMA A/B frag)
typedef __attribute__((ext_vector_type(4))) float floatx4;  // MFMA C/D frag

typedef const __attribute__((address_space(1))) void* gptr_t;
typedef __attribute__((address_space(3))) void* lptr_t;

// async global->LDS, 16B per lane. LDS dest = wave-uniform base + lane*16.
__device__ __forceinline__ void load_lds16(const bf16* g, bf16* l) {
    __builtin_amdgcn_global_load_lds((gptr_t)(uintptr_t)(const void*)g,
                                     (lptr_t)(uintptr_t)(void*)l, 16, 0, 0);
}

// wait until at most N vector-memory ops outstanding. gfx9 vmcnt is 6 bits
// split lo[3:0]=bits3:0, hi[5:4]=bits15:14; lgkm/exp left at max (no wait).
#define WAIT_VM(n) __builtin_amdgcn_s_waitcnt(0x0F70 | ((n) & 15) | (((n) >> 4) << 14))

// tanh(x) = 1 - 2/(exp(2x)+1); saturates correctly at +-inf; err << bf16 ulp.
__device__ __forceinline__ float fast_tanh(float x) {
    float e = __expf(2.f * x);
    return 1.f - 2.f / (e + 1.f);
}

// ---------------------------------------------------------------------------
// Layers 1 & 2: C = tanh(A·W^T + b). r7 structure: 128x128 block, 4 waves
// (wave tile 64x64), double-buffered LDS (2 x 32 KB = 64 KB) ->
// __launch_bounds__(256,2) gives 2 blocks/CU = 8 waves/CU = 2 waves/SIMD.
// Rationale (r6 post-mortem): per-CU per k32 this structure is near-balanced
// (LDS ~900 cyc vs MFMA ~620 cyc at the corrected 4.85 cyc/MFMA PER CU), but
// r6's 144 KB single-block config had 1 wave/SIMD — each wave serializes its
// own ds_read->MFMA chain and both pipes sit ~60% idle. 2 waves/SIMD gives
// cross-wave overlap (m114). Grid 512 blocks. Fine-grained WAIT_VM(8) keeps
// next tile's staging in flight across the barrier. XCD swizzle: the 8
// n-tiles of one m-stripe land on one XCD (A re-reads hit local L2).
// XOR-8 chunk swizzle keeps frag ds_read_b128 at free 2-way bank aliasing.
// ---------------------------------------------------------------------------
__global__ void __launch_bounds__(256, 2)
gemm_tanh4(const bf16* __restrict__ A, const bf16* __restrict__ W,
           const float* __restrict__ bias, bf16* __restrict__ out,
           int K, int N) {
    constexpr int BM = 128, BN = 128, MT = 4, NT = 4;
    __shared__ alignas(16) bf16 lA[2][BM * 64];     // 2 x 16 KB
    __shared__ alignas(16) bf16 lB[2][BN * 64];     // 2 x 16 KB

    // XCD swizzle: hw round-robins dispatch index b -> XCD b&7. Blocks with
    // the same m-stripe (8 n-tiles) get indices == c (mod 8) -> one XCD.
    const int b   = blockIdx.x + gridDim.x * blockIdx.y;   // grid (8, 64)
    const int xcd = b & 7, j = b >> 3;
    const int bx  = j & 7;                 // n-tile 0..7
    const int by  = xcd + 8 * (j >> 3);    // m-stripe 0..63

    const int tid  = threadIdx.x;
    const int lane = tid & 63;
    const int w    = tid >> 6;
    const int wr   = w >> 1, wc = w & 1;
    const int quad = lane >> 4, l16 = lane & 15;
    const int brow = by * BM;
    const int bcol = bx * BN;

    // staging: per tile 1024 A-chunks + 1024 B-chunks; 4+4 per thread.
    const bf16* gA[4]; const bf16* gW[4]; int lq[4];
#pragma unroll
    for (int jj = 0; jj < 4; ++jj) {
        const int q = tid + jj * 256;
        const int r = q >> 3, s = (q & 7) ^ (r & 7);
        gA[jj] = A + (size_t)(brow + r) * K + s * 8;
        gW[jj] = W + (size_t)(bcol + r) * K + s * 8;
        lq[jj] = q * 8;
    }

    floatx4 acc[MT][NT];
    const floatx4 zero = {0.f, 0.f, 0.f, 0.f};
#pragma unroll
    for (int mt = 0; mt < MT; ++mt)
#pragma unroll
        for (int nt = 0; nt < NT; ++nt) acc[mt][nt] = zero;

    const int arow0 = wr * 64 + l16;
    const int brow0 = wc * 64 + l16;
    const int x7 = l16 & 7;

    const int nIter = K / 64;   // 8 (K=512) or 16 (K=1024)
    // prologue: stage tile 0 into buffer 0 (8 loads/thread)
#pragma unroll
    for (int jj = 0; jj < 4; ++jj) load_lds16(gA[jj], &lA[0][0] + lq[jj]);
#pragma unroll
    for (int jj = 0; jj < 4; ++jj) load_lds16(gW[jj], &lB[0][0] + lq[jj]);

    for (int kt = 0; kt < nIter; ++kt) {
        const int cur = kt & 1;
        if (kt + 1 < nIter) {
            // issue tile kt+1 into the other buffer (freed at the trailing
            // barrier of iteration kt-1); then wait for OUR tile only:
            // <=16 outstanding, oldest 8 are tile kt.
#pragma unroll
            for (int jj = 0; jj < 4; ++jj)
                load_lds16(gA[jj] + (kt + 1) * 64, &lA[cur ^ 1][0] + lq[jj]);
#pragma unroll
            for (int jj = 0; jj < 4; ++jj)
                load_lds16(gW[jj] + (kt + 1) * 64, &lB[cur ^ 1][0] + lq[jj]);
            WAIT_VM(8);
        } else {
            WAIT_VM(0);
        }
        __builtin_amdgcn_s_barrier();              // publish tile kt

#pragma unroll
        for (int kk = 0; kk < 2; ++kk) {
            const int sw = ((kk * 4 + quad) ^ x7) * 8;
            short8 af[MT], bfr[NT];
#pragma unroll
            for (int mt = 0; mt < MT; ++mt)
                af[mt] = *(const short8*)(&lA[cur][0] + (arow0 + mt * 16) * 64 + sw);
#pragma unroll
            for (int nt = 0; nt < NT; ++nt)
                bfr[nt] = *(const short8*)(&lB[cur][0] + (brow0 + nt * 16) * 64 + sw);
#pragma unroll
            for (int mt = 0; mt < MT; ++mt)
#pragma unroll
                for (int nt = 0; nt < NT; ++nt)
                    acc[mt][nt] = __builtin_amdgcn_mfma_f32_16x16x32_bf16(
                        af[mt], bfr[nt], acc[mt][nt], 0, 0, 0);
        }
        __builtin_amdgcn_s_barrier();              // retire tile kt
    }

    const int m0 = brow + wr * 64 + quad * 4;
    const int n0 = bcol + wc * 64 + l16;
#pragma unroll
    for (int mt = 0; mt < MT; ++mt)
#pragma unroll
        for (int nt = 0; nt < NT; ++nt) {
            const int n = n0 + nt * 16;
            const float bb = bias[n];
#pragma unroll
            for (int i = 0; i < 4; ++i) {
                const int m = m0 + mt * 16 + i;
                out[(size_t)m * N + n] = __float2bfloat16(fast_tanh(acc[mt][nt][i] + bb));
            }
        }
}

// ---------------------------------------------------------------------------
// LDS-staged 2-barrier core for gemm_k (memory-bound, ~its floor).
// brow/bcol passed in (XCD-swizzled by caller).
// ---------------------------------------------------------------------------
template<int BM, int BN, int WR, int WC>
__device__ __forceinline__ void gemm_core(const bf16* __restrict__ A,
                                          const bf16* __restrict__ W,
                                          int K, int brow, int bcol,
                                          floatx4 (&acc)[BM / WR / 16][BN / WC / 16],
                                          bf16* lA, bf16* lB) {
    constexpr int MT = BM / WR / 16, NT = BN / WC / 16;
    constexpr int THREADS = WR * WC * 64;
    constexpr int AL = BM * 8 / THREADS;
    constexpr int BL = BN * 8 / THREADS;

    const int tid  = threadIdx.x;
    const int lane = tid & 63;
    const int w    = tid >> 6;
    const int wr   = w / WC, wc = w % WC;
    const int quad = lane >> 4, l16 = lane & 15;

    const bf16* gA[AL]; const bf16* gW[BL];
    bf16* lAd[AL]; bf16* lBd[BL];
#pragma unroll
    for (int j = 0; j < AL; ++j) {
        const int q = tid + j * THREADS;
        const int r = q >> 3, s = (q & 7) ^ (r & 7);
        gA[j]  = A + (size_t)(brow + r) * K + s * 8;
        lAd[j] = lA + q * 8;
    }
#pragma unroll
    for (int j = 0; j < BL; ++j) {
        const int q = tid + j * THREADS;
        const int r = q >> 3, s = (q & 7) ^ (r & 7);
        gW[j]  = W + (size_t)(bcol + r) * K + s * 8;
        lBd[j] = lB + q * 8;
    }

    const floatx4 zero = {0.f, 0.f, 0.f, 0.f};
#pragma unroll
    for (int mt = 0; mt < MT; ++mt)
#pragma unroll
        for (int nt = 0; nt < NT; ++nt) acc[mt][nt] = zero;

    const int arow = wr * (BM / WR) + l16;
    const int brw  = wc * (BN / WC) + l16;
    const int x7   = l16 & 7;

    const int nIter = K / 64;
    for (int kt = 0; kt < nIter; ++kt) {
#pragma unroll
        for (int j = 0; j < AL; ++j) load_lds16(gA[j], lAd[j]);
#pragma unroll
        for (int j = 0; j < BL; ++j) load_lds16(gW[j], lBd[j]);
        __syncthreads();

#pragma unroll
        for (int kk = 0; kk < 2; ++kk) {
            const int sw = ((kk * 4 + quad) ^ x7) * 8;
            short8 af[MT], bfr[NT];
#pragma unroll
            for (int mt = 0; mt < MT; ++mt)
                af[mt] = *(const short8*)(lA + (arow + mt * 16) * 64 + sw);
#pragma unroll
            for (int nt = 0; nt < NT; ++nt)
                bfr[nt] = *(const short8*)(lB + (brw + nt * 16) * 64 + sw);
#pragma unroll
            for (int mt = 0; mt < MT; ++mt)
#pragma unroll
                for (int nt = 0; nt < NT; ++nt)
                    acc[mt][nt] = __builtin_amdgcn_mfma_f32_16x16x32_bf16(
                        af[mt], bfr[nt], acc[mt][nt], 0, 0, 0);
        }
        __syncthreads();

#pragma unroll
        for (int j = 0; j < AL; ++j) gA[j] += 64;
#pragma unroll
        for (int j = 0; j < BL; ++j) gW[j] += 64;
    }
}

// Layer-3 GEMM (N=512, K=1024) with fused RK4 logic. 64x64 tile, 4 waves,
// 4 blocks/CU. kv = acc + b3[n].
// mode 0 (k1):   kacc = kv;     x0 = bf16(hb + alpha*kv + te)
// mode 1 (k2/3): kacc += 2*kv;  x0 = bf16(hb + alpha*kv + te)
// mode 2 (k4):   hn = h_f32 + dt6*(kacc + kv); h_out=hn; hb_out=bf16(hn);
//                if (x0_out) x0 = bf16(hn + te)
// Modes 0/1 read h as bf16 (halves h-read traffic); its rounding only enters
// x0, which is bf16-rounded anyway. Mode 2 keeps the exact fp32 h.
__global__ void __launch_bounds__(256, 4)
gemm_k(const bf16* __restrict__ A, const bf16* __restrict__ W,
       const float* __restrict__ bias, int K,
       bf16* __restrict__ kacc, const bf16* __restrict__ hb_src,
       const float* __restrict__ h_src, float* __restrict__ h_out,
       bf16* __restrict__ hb_out, bf16* __restrict__ x0_out,
       const float* __restrict__ temb, float alpha, float dt6, int mode) {
    constexpr int BM = 64, BN = 64, WR = 2, WC = 2;
    constexpr int MT = 2, NT = 2;
    __shared__ alignas(16) bf16 lA[BM * 64];
    __shared__ alignas(16) bf16 lB[BN * 64];

    // XCD swizzle: the 8 n-tiles sharing an A-row stripe -> one XCD.
    const int b   = blockIdx.x + gridDim.x * blockIdx.y;   // grid (8,128)
    const int xcd = b & 7, j = b >> 3;
    const int bx  = j & 7;
    const int by  = xcd + 8 * (j >> 3);

    floatx4 acc[MT][NT];
    gemm_core<BM, BN, WR, WC>(A, W, K, by * BM, bx * BN, acc, lA, lB);

    const int tid = threadIdx.x;
    const int lane = tid & 63, w = tid >> 6;
    const int wr = w / WC, wc = w % WC;
    const int quad = lane >> 4, l16 = lane & 15;
    const int m0 = by * BM + wr * (BM / WR) + quad * 4;
    const int n0 = bx * BN + wc * (BN / WC) + l16;

#pragma unroll
    for (int mt = 0; mt < MT; ++mt)
#pragma unroll
        for (int nt = 0; nt < NT; ++nt) {
            const int n = n0 + nt * 16;
            const float bb = bias[n];
            const float te = temb[n];
#pragma unroll
            for (int i = 0; i < 4; ++i) {
                const int m = m0 + mt * 16 + i;
                const size_t idx = (size_t)m * 512 + n;
                const float kv = acc[mt][nt][i] + bb;
                if (mode == 0) {
                    kacc[idx] = __float2bfloat16(kv);
                    x0_out[idx] = __float2bfloat16(
                        __bfloat162float(hb_src[idx]) + alpha * kv + te);
                } else if (mode == 1) {
                    kacc[idx] = __float2bfloat16(__bfloat162float(kacc[idx]) + 2.f * kv);
                    x0_out[idx] = __float2bfloat16(
                        __bfloat162float(hb_src[idx]) + alpha * kv + te);
                } else {
                    const float hn = h_src[idx] + dt6 * (__bfloat162float(kacc[idx]) + kv);
                    h_out[idx] = hn;
                    hb_out[idx] = __float2bfloat16(hn);
                    if (x0_out) x0_out[idx] = __float2bfloat16(hn + te);
                }
            }
        }
}

__global__ void f2b_kern(const float* __restrict__ src, bf16* __restrict__ dst, int n) {
    const int i = blockIdx.x * blockDim.x + threadIdx.x;
    if (i < n) dst[i] = __float2bfloat16(src[i]);
}

// temb[j][n] = (j*dt/2)*Wt[n] + bt[n], j = 0..20
__global__ void temb_kern(const float* __restrict__ Wt, const float* __restrict__ bt,
                          float* __restrict__ temb, float half_dt, int total) {
    const int i = blockIdx.x * blockDim.x + threadIdx.x;
    if (i < total) {
        const int j = i >> 9, n = i & 511;
        temb[i] = (j * half_dt) * Wt[n] + bt[n];
    }
}

__global__ void prep_kern(const float* __restrict__ h, const float* __restrict__ temb0,
                          bf16* __restrict__ x0, bf16* __restrict__ hb, int total) {
    const int i = blockIdx.x * blockDim.x + threadIdx.x;
    if (i < total) {
        const float hv = h[i];
        x0[i] = __float2bfloat16(hv + temb0[i & 511]);
        hb[i] = __float2bfloat16(hv);
    }
}

extern "C" void kernel_launch(void* const* d_in, const int* in_sizes, int n_in,
                              void* d_out, int out_size, void* d_ws, size_t ws_size,
                              hipStream_t stream) {
    const float* h_in = (const float*)d_in[0];
    const float* W1 = (const float*)d_in[1];
    const float* b1 = (const float*)d_in[2];
    const float* W2 = (const float*)d_in[3];
    const float* b2 = (const float*)d_in[4];
    const float* W3 = (const float*)d_in[5];
    const float* b3 = (const float*)d_in[6];
    const float* Wt = (const float*)d_in[7];
    const float* bt = (const float*)d_in[8];
    // n_steps (d_in[9]) is a fixed Python scalar = 10.
    const int B = 8192, H = 512, H2 = 1024, NS = 10;
    const float dt = 1.f / NS;

    char* ws = (char*)d_ws;
    auto alloc = [&](size_t bytes) {
        char* p = ws;
        ws += (bytes + 255) & ~(size_t)255;
        return p;
    };
    bf16* W1b = (bf16*)alloc((size_t)H2 * H * 2);
    bf16* W2b = (bf16*)alloc((size_t)H2 * H2 * 2);
    bf16* W3b = (bf16*)alloc((size_t)H * H2 * 2);
    bf16* x0b = (bf16*)alloc((size_t)B * H * 2);
    bf16* x1b = (bf16*)alloc((size_t)B * H2 * 2);
    bf16* x2b = (bf16*)alloc((size_t)B * H2 * 2);
    bf16* kacc = (bf16*)alloc((size_t)B * H * 2);
    bf16* hb   = (bf16*)alloc((size_t)B * H * 2);
    float* temb = (float*)alloc((size_t)21 * H * 4);
    float* hbuf = (float*)d_out;  // h ping-pongs through d_out (fp32)

    {
        int n = H2 * H;
        f2b_kern<<<(n + 255) / 256, 256, 0, stream>>>(W1, W1b, n);
        n = H2 * H2;
        f2b_kern<<<(n + 255) / 256, 256, 0, stream>>>(W2, W2b, n);
        n = H * H2;
        f2b_kern<<<(n + 255) / 256, 256, 0, stream>>>(W3, W3b, n);
    }
    {
        const int total = 21 * H;
        temb_kern<<<(total + 255) / 256, 256, 0, stream>>>(Wt, bt, temb, dt * 0.5f, total);
    }
    {
        const int total = B * H;
        prep_kern<<<(total + 255) / 256, 256, 0, stream>>>(h_in, temb, x0b, hb, total);
    }

    const dim3 blk256(256);
    const dim3 g12(H2 / 128, B / 128);  // 8 x 64 = 512 blocks (2/CU)
    const dim3 g3(H / 64, B / 64);      // 8 x 128 = 1024 blocks (4/CU)

    for (int s = 0; s < NS; ++s) {
        const float* hs = (s == 0) ? h_in : hbuf;
        const float* tmid = temb + (size_t)(2 * s + 1) * H;
        const float* tend = temb + (size_t)(2 * s + 2) * H;
        for (int e = 0; e < 4; ++e) {
            gemm_tanh4<<<g12, blk256, 0, stream>>>(x0b, W1b, b1, x1b, H, H2);
            gemm_tanh4<<<g12, blk256, 0, stream>>>(x1b, W2b, b2, x2b, H2, H2);
            if (e == 0)
                gemm_k<<<g3, blk256, 0, stream>>>(x2b, W3b, b3, H2, kacc, hb, hs,
                                                  nullptr, nullptr, x0b, tmid,
                                                  dt * 0.5f, 0.f, 0);
            else if (e == 1)
                gemm_k<<<g3, blk256, 0, stream>>>(x2b, W3b, b3, H2, kacc, hb, hs,
                                                  nullptr, nullptr, x0b, tmid,
                                                  dt * 0.5f, 0.f, 1);
            else if (e == 2)
                gemm_k<<<g3, blk256, 0, stream>>>(x2b, W3b, b3, H2, kacc, hb, hs,
                                                  nullptr, nullptr, x0b, tend,
                                                  dt, 0.f, 1);
            else
                gemm_k<<<g3, blk256, 0, stream>>>(x2b, W3b, b3, H2, kacc, hb, hs,
                                                  hbuf, hb,
                                                  (s == NS - 1) ? nullptr : x0b,
                                                  tend, 0.f, dt / 6.f, 2);
        }
    }
}

// Round 9
// 2248.866 us; speedup vs baseline: 1.5375x; 1.0790x over previous
//
#include <hip/hip_runtime.h>
#include <hip/hip_bf16.h>
#include <math.h>
#include <stdint.h>

using bf16 = __hip_bfloat16;
typedef __attribute__((ext_vector_type(8))) short short8;   // 8 bf16 (MFMA A/B frag)
typedef __attribute__((ext_vector_type(4))) float floatx4;  // MFMA C/D frag (f32)
typedef __attribute__((ext_vector_type(4))) int int4v;      // i8 K=64 frag / i32 acc

typedef const __attribute__((address_space(1))) void* gptr_t;
typedef __attribute__((address_space(3))) void* lptr_t;

__device__ __forceinline__ void load_lds16(const void* g, void* l) {
    __builtin_amdgcn_global_load_lds((gptr_t)(uintptr_t)g, (lptr_t)(uintptr_t)l, 16, 0, 0);
}

// wait until at most N vector-memory ops outstanding. gfx9 vmcnt 6 bits:
// lo[3:0]=bits3:0, hi[5:4]=bits15:14; lgkm/exp left at max (no wait).
#define WAIT_VM(n) __builtin_amdgcn_s_waitcnt(0x0F70 | ((n) & 15) | (((n) >> 4) << 14))

// tanh(x) = 1 - 2/(exp(2x)+1)
__device__ __forceinline__ float fast_tanh(float x) {
    float e = __expf(2.f * x);
    return 1.f - 2.f / (e + 1.f);
}

// ---------------------------------------------------------------------------
// L1: C = tanh(A·W^T + b), bf16 core (r7 structure: 128x128, 4 waves, wave
// tile 64x64, dbuf 64 KB, 2 blocks/CU, fine WAIT_VM, XCD swizzle).
// Output written as i8 (x1*127) — consumed by the i8 L2. tanh out in (-1,1):
// linear i8 gives delta_x RMS ~0.0023, 8x better than e4m3's ~0.018 (the
// r8 near-miss: absmax 0.195 vs 0.152 was pure e4m3 mantissa noise; the
// MX fragment layout itself was correct).
// ---------------------------------------------------------------------------
__global__ void __launch_bounds__(256, 2)
gemm_tanh4(const bf16* __restrict__ A, const bf16* __restrict__ W,
           const float* __restrict__ bias, int8_t* __restrict__ out,
           int K, int N) {
    constexpr int BM = 128, BN = 128, MT = 4, NT = 4;
    __shared__ alignas(16) bf16 lA[2][BM * 64];
    __shared__ alignas(16) bf16 lB[2][BN * 64];

    const int b   = blockIdx.x + gridDim.x * blockIdx.y;   // grid (8, 64)
    const int xcd = b & 7, j = b >> 3;
    const int bx  = j & 7;
    const int by  = xcd + 8 * (j >> 3);

    const int tid  = threadIdx.x;
    const int lane = tid & 63;
    const int w    = tid >> 6;
    const int wr   = w >> 1, wc = w & 1;
    const int quad = lane >> 4, l16 = lane & 15;
    const int brow = by * BM;
    const int bcol = bx * BN;

    const bf16* gA[4]; const bf16* gW[4]; int lq[4];
#pragma unroll
    for (int jj = 0; jj < 4; ++jj) {
        const int q = tid + jj * 256;
        const int r = q >> 3, s = (q & 7) ^ (r & 7);
        gA[jj] = A + (size_t)(brow + r) * K + s * 8;
        gW[jj] = W + (size_t)(bcol + r) * K + s * 8;
        lq[jj] = q * 8;
    }

    floatx4 acc[MT][NT];
    const floatx4 zero = {0.f, 0.f, 0.f, 0.f};
#pragma unroll
    for (int mt = 0; mt < MT; ++mt)
#pragma unroll
        for (int nt = 0; nt < NT; ++nt) acc[mt][nt] = zero;

    const int arow0 = wr * 64 + l16;
    const int brow0 = wc * 64 + l16;
    const int x7 = l16 & 7;

    const int nIter = K / 64;
#pragma unroll
    for (int jj = 0; jj < 4; ++jj) load_lds16(gA[jj], &lA[0][0] + lq[jj]);
#pragma unroll
    for (int jj = 0; jj < 4; ++jj) load_lds16(gW[jj], &lB[0][0] + lq[jj]);

    for (int kt = 0; kt < nIter; ++kt) {
        const int cur = kt & 1;
        if (kt + 1 < nIter) {
#pragma unroll
            for (int jj = 0; jj < 4; ++jj)
                load_lds16(gA[jj] + (kt + 1) * 64, &lA[cur ^ 1][0] + lq[jj]);
#pragma unroll
            for (int jj = 0; jj < 4; ++jj)
                load_lds16(gW[jj] + (kt + 1) * 64, &lB[cur ^ 1][0] + lq[jj]);
            WAIT_VM(8);
        } else {
            WAIT_VM(0);
        }
        __builtin_amdgcn_s_barrier();

#pragma unroll
        for (int kk = 0; kk < 2; ++kk) {
            const int sw = ((kk * 4 + quad) ^ x7) * 8;
            short8 af[MT], bfr[NT];
#pragma unroll
            for (int mt = 0; mt < MT; ++mt)
                af[mt] = *(const short8*)(&lA[cur][0] + (arow0 + mt * 16) * 64 + sw);
#pragma unroll
            for (int nt = 0; nt < NT; ++nt)
                bfr[nt] = *(const short8*)(&lB[cur][0] + (brow0 + nt * 16) * 64 + sw);
#pragma unroll
            for (int mt = 0; mt < MT; ++mt)
#pragma unroll
                for (int nt = 0; nt < NT; ++nt)
                    acc[mt][nt] = __builtin_amdgcn_mfma_f32_16x16x32_bf16(
                        af[mt], bfr[nt], acc[mt][nt], 0, 0, 0);
        }
        __builtin_amdgcn_s_barrier();
    }

    const int m0 = brow + wr * 64 + quad * 4;
    const int n0 = bcol + wc * 64 + l16;
#pragma unroll
    for (int mt = 0; mt < MT; ++mt)
#pragma unroll
        for (int nt = 0; nt < NT; ++nt) {
            const int n = n0 + nt * 16;
            const float bb = bias[n];
#pragma unroll
            for (int i = 0; i < 4; ++i) {
                const int m = m0 + mt * 16 + i;
                const float t = fast_tanh(acc[mt][nt][i] + bb);
                out[(size_t)m * N + n] = (int8_t)__float2int_rn(t * 127.f);
            }
        }
}

// ---------------------------------------------------------------------------
// L2: C = tanh(acc*dq[n] + b2), i8 core. A = x1*127 (i8), W = per-row-scaled
// i8 W2 (row n scaled by 127/rowmax_n), dq[n] = rowmax_n/127^2 dequant.
// mfma_i32_16x16x64_i8: frag = 16 contiguous k-bytes/lane (quad-strided) —
// byte-identical to the low/high half of r8's verified fp8 K=128 frag, so
// the staging layout is reused unchanged: 128-B rows, XOR-8 swizzle on 16-B
// chunks (slot p of row r holds chunk p^(r&7)); per kk, slot formula matches
// the bf16 kernel's free-2-way pattern. Per-CU per k128 vs bf16: LDS reads
// halved (16 vs 32 b128/wave), MFMA cyc ~halved (2x16 i8 MFMA @ ~4.6 cyc vs
// 4x16 bf16 @ ~4.85). dbuf 2 x (16+16) KB = 64 KB, 2 blk/CU, XCD swizzle.
// ---------------------------------------------------------------------------
__global__ void __launch_bounds__(256, 2)
gemm_tanh_i8(const int8_t* __restrict__ A, const int8_t* __restrict__ W,
             const float* __restrict__ dq, const float* __restrict__ bias,
             bf16* __restrict__ out, int K, int N) {
    constexpr int BM = 128, BN = 128, MT = 4, NT = 4;
    __shared__ alignas(16) int8_t lA[2][BM * 128];   // 2 x 16 KB
    __shared__ alignas(16) int8_t lB[2][BN * 128];   // 2 x 16 KB

    const int b   = blockIdx.x + gridDim.x * blockIdx.y;   // grid (8, 64)
    const int xcd = b & 7, j = b >> 3;
    const int bx  = j & 7;
    const int by  = xcd + 8 * (j >> 3);

    const int tid  = threadIdx.x;
    const int lane = tid & 63;
    const int w    = tid >> 6;
    const int wr   = w >> 1, wc = w & 1;
    const int quad = lane >> 4, l16 = lane & 15;
    const int brow = by * BM;
    const int bcol = bx * BN;

    // staging: per tile 128 rows x 8 chunks of 16 B per matrix; 4+4 /thread
    const int8_t* gA[4]; const int8_t* gW[4]; int lq[4];
#pragma unroll
    for (int jj = 0; jj < 4; ++jj) {
        const int q = tid + jj * 256;
        const int r = q >> 3, s = (q & 7) ^ (r & 7);
        gA[jj] = A + (size_t)(brow + r) * K + s * 16;
        gW[jj] = W + (size_t)(bcol + r) * K + s * 16;
        lq[jj] = q * 16;
    }

    int4v acc[MT][NT];
    const int4v izero = {0, 0, 0, 0};
#pragma unroll
    for (int mt = 0; mt < MT; ++mt)
#pragma unroll
        for (int nt = 0; nt < NT; ++nt) acc[mt][nt] = izero;

    const int arow0 = wr * 64 + l16;
    const int brow0 = wc * 64 + l16;
    const int x7 = l16 & 7;

    const int nIter = K / 128;   // 8 for K=1024
#pragma unroll
    for (int jj = 0; jj < 4; ++jj) load_lds16(gA[jj], &lA[0][0] + lq[jj]);
#pragma unroll
    for (int jj = 0; jj < 4; ++jj) load_lds16(gW[jj], &lB[0][0] + lq[jj]);

    for (int kt = 0; kt < nIter; ++kt) {
        const int cur = kt & 1;
        if (kt + 1 < nIter) {
#pragma unroll
            for (int jj = 0; jj < 4; ++jj)
                load_lds16(gA[jj] + (kt + 1) * 128, &lA[cur ^ 1][0] + lq[jj]);
#pragma unroll
            for (int jj = 0; jj < 4; ++jj)
                load_lds16(gW[jj] + (kt + 1) * 128, &lB[cur ^ 1][0] + lq[jj]);
            WAIT_VM(8);
        } else {
            WAIT_VM(0);
        }
        __builtin_amdgcn_s_barrier();

        // two K=64 MFMA groups per staged k128
#pragma unroll
        for (int kk = 0; kk < 2; ++kk) {
            const int sw = ((kk * 4 + quad) ^ x7) * 16;
            int4v af[MT], bfr[NT];
#pragma unroll
            for (int mt = 0; mt < MT; ++mt)
                af[mt] = *(const int4v*)(&lA[cur][(arow0 + mt * 16) * 128 + sw]);
#pragma unroll
            for (int nt = 0; nt < NT; ++nt)
                bfr[nt] = *(const int4v*)(&lB[cur][(brow0 + nt * 16) * 128 + sw]);
#pragma unroll
            for (int mt = 0; mt < MT; ++mt)
#pragma unroll
                for (int nt = 0; nt < NT; ++nt)
                    acc[mt][nt] = __builtin_amdgcn_mfma_i32_16x16x64_i8(
                        af[mt], bfr[nt], acc[mt][nt], 0, 0, 0);
        }
        __builtin_amdgcn_s_barrier();
    }

    const int m0 = brow + wr * 64 + quad * 4;
    const int n0 = bcol + wc * 64 + l16;
#pragma unroll
    for (int mt = 0; mt < MT; ++mt)
#pragma unroll
        for (int nt = 0; nt < NT; ++nt) {
            const int n = n0 + nt * 16;
            const float bb = bias[n];
            const float dqn = dq[n];
#pragma unroll
            for (int i = 0; i < 4; ++i) {
                const int m = m0 + mt * 16 + i;
                out[(size_t)m * N + n] =
                    __float2bfloat16(fast_tanh((float)acc[mt][nt][i] * dqn + bb));
            }
        }
}

// ---------------------------------------------------------------------------
// LDS-staged 2-barrier bf16 core for gemm_k (memory-bound, ~its floor).
// ---------------------------------------------------------------------------
template<int BM, int BN, int WR, int WC>
__device__ __forceinline__ void gemm_core(const bf16* __restrict__ A,
                                          const bf16* __restrict__ W,
                                          int K, int brow, int bcol,
                                          floatx4 (&acc)[BM / WR / 16][BN / WC / 16],
                                          bf16* lA, bf16* lB) {
    constexpr int MT = BM / WR / 16, NT = BN / WC / 16;
    constexpr int THREADS = WR * WC * 64;
    constexpr int AL = BM * 8 / THREADS;
    constexpr int BL = BN * 8 / THREADS;

    const int tid  = threadIdx.x;
    const int lane = tid & 63;
    const int w    = tid >> 6;
    const int wr   = w / WC, wc = w % WC;
    const int quad = lane >> 4, l16 = lane & 15;

    const bf16* gA[AL]; const bf16* gW[BL];
    bf16* lAd[AL]; bf16* lBd[BL];
#pragma unroll
    for (int j = 0; j < AL; ++j) {
        const int q = tid + j * THREADS;
        const int r = q >> 3, s = (q & 7) ^ (r & 7);
        gA[j]  = A + (size_t)(brow + r) * K + s * 8;
        lAd[j] = lA + q * 8;
    }
#pragma unroll
    for (int j = 0; j < BL; ++j) {
        const int q = tid + j * THREADS;
        const int r = q >> 3, s = (q & 7) ^ (r & 7);
        gW[j]  = W + (size_t)(bcol + r) * K + s * 8;
        lBd[j] = lB + q * 8;
    }

    const floatx4 zero = {0.f, 0.f, 0.f, 0.f};
#pragma unroll
    for (int mt = 0; mt < MT; ++mt)
#pragma unroll
        for (int nt = 0; nt < NT; ++nt) acc[mt][nt] = zero;

    const int arow = wr * (BM / WR) + l16;
    const int brw  = wc * (BN / WC) + l16;
    const int x7   = l16 & 7;

    const int nIter = K / 64;
    for (int kt = 0; kt < nIter; ++kt) {
#pragma unroll
        for (int j = 0; j < AL; ++j) load_lds16(gA[j], lAd[j]);
#pragma unroll
        for (int j = 0; j < BL; ++j) load_lds16(gW[j], lBd[j]);
        __syncthreads();

#pragma unroll
        for (int kk = 0; kk < 2; ++kk) {
            const int sw = ((kk * 4 + quad) ^ x7) * 8;
            short8 af[MT], bfr[NT];
#pragma unroll
            for (int mt = 0; mt < MT; ++mt)
                af[mt] = *(const short8*)(lA + (arow + mt * 16) * 64 + sw);
#pragma unroll
            for (int nt = 0; nt < NT; ++nt)
                bfr[nt] = *(const short8*)(lB + (brw + nt * 16) * 64 + sw);
#pragma unroll
            for (int mt = 0; mt < MT; ++mt)
#pragma unroll
                for (int nt = 0; nt < NT; ++nt)
                    acc[mt][nt] = __builtin_amdgcn_mfma_f32_16x16x32_bf16(
                        af[mt], bfr[nt], acc[mt][nt], 0, 0, 0);
        }
        __syncthreads();

#pragma unroll
        for (int j = 0; j < AL; ++j) gA[j] += 64;
#pragma unroll
        for (int j = 0; j < BL; ++j) gW[j] += 64;
    }
}

// Layer-3 GEMM (N=512, K=1024) with fused RK4 logic. 64x64 tile, 4 waves,
// 4 blocks/CU. kv = acc + b3[n].
// mode 0 (k1):   kacc = kv;     x0 = bf16(hb + alpha*kv + te)
// mode 1 (k2/3): kacc += 2*kv;  x0 = bf16(hb + alpha*kv + te)
// mode 2 (k4):   hn = h_f32 + dt6*(kacc + kv); h_out=hn; hb_out=bf16(hn);
//                if (x0_out) x0 = bf16(hn + te)
__global__ void __launch_bounds__(256, 4)
gemm_k(const bf16* __restrict__ A, const bf16* __restrict__ W,
       const float* __restrict__ bias, int K,
       bf16* __restrict__ kacc, const bf16* __restrict__ hb_src,
       const float* __restrict__ h_src, float* __restrict__ h_out,
       bf16* __restrict__ hb_out, bf16* __restrict__ x0_out,
       const float* __restrict__ temb, float alpha, float dt6, int mode) {
    constexpr int BM = 64, BN = 64, WR = 2, WC = 2;
    constexpr int MT = 2, NT = 2;
    __shared__ alignas(16) bf16 lA[BM * 64];
    __shared__ alignas(16) bf16 lB[BN * 64];

    const int b   = blockIdx.x + gridDim.x * blockIdx.y;   // grid (8,128)
    const int xcd = b & 7, j = b >> 3;
    const int bx  = j & 7;
    const int by  = xcd + 8 * (j >> 3);

    floatx4 acc[MT][NT];
    gemm_core<BM, BN, WR, WC>(A, W, K, by * BM, bx * BN, acc, lA, lB);

    const int tid = threadIdx.x;
    const int lane = tid & 63, w = tid >> 6;
    const int wr = w / WC, wc = w % WC;
    const int quad = lane >> 4, l16 = lane & 15;
    const int m0 = by * BM + wr * (BM / WR) + quad * 4;
    const int n0 = bx * BN + wc * (BN / WC) + l16;

#pragma unroll
    for (int mt = 0; mt < MT; ++mt)
#pragma unroll
        for (int nt = 0; nt < NT; ++nt) {
            const int n = n0 + nt * 16;
            const float bb = bias[n];
            const float te = temb[n];
#pragma unroll
            for (int i = 0; i < 4; ++i) {
                const int m = m0 + mt * 16 + i;
                const size_t idx = (size_t)m * 512 + n;
                const float kv = acc[mt][nt][i] + bb;
                if (mode == 0) {
                    kacc[idx] = __float2bfloat16(kv);
                    x0_out[idx] = __float2bfloat16(
                        __bfloat162float(hb_src[idx]) + alpha * kv + te);
                } else if (mode == 1) {
                    kacc[idx] = __float2bfloat16(__bfloat162float(kacc[idx]) + 2.f * kv);
                    x0_out[idx] = __float2bfloat16(
                        __bfloat162float(hb_src[idx]) + alpha * kv + te);
                } else {
                    const float hn = h_src[idx] + dt6 * (__bfloat162float(kacc[idx]) + kv);
                    h_out[idx] = hn;
                    hb_out[idx] = __float2bfloat16(hn);
                    if (x0_out) x0_out[idx] = __float2bfloat16(hn + te);
                }
            }
        }
}

__global__ void f2b_kern(const float* __restrict__ src, bf16* __restrict__ dst, int n) {
    const int i = blockIdx.x * blockDim.x + threadIdx.x;
    if (i < n) dst[i] = __float2bfloat16(src[i]);
}

// Per-row i8 quantization of W2 (N=1024 rows, K=1024): row n scaled by
// 127/rowmax_n (clamped), dq[n] = rowmax_n/127^2 (includes x1's /127).
__global__ void quantW2_row(const float* __restrict__ W, int K,
                            int8_t* __restrict__ out, float* __restrict__ dq) {
    __shared__ float red[256];
    const int row = blockIdx.x, tid = threadIdx.x;
    const float* src = W + (size_t)row * K;
    float m = 0.f;
    for (int k = tid; k < K; k += 256) m = fmaxf(m, fabsf(src[k]));
    red[tid] = m;
    __syncthreads();
    for (int s = 128; s > 0; s >>= 1) {
        if (tid < s) red[tid] = fmaxf(red[tid], red[tid + s]);
        __syncthreads();
    }
    const float rmax = fmaxf(red[0], 1e-8f);
    const float sc = 127.f / rmax;
    int8_t* dst = out + (size_t)row * K;
    for (int k = tid; k < K; k += 256) {
        int v = __float2int_rn(src[k] * sc);
        v = v > 127 ? 127 : (v < -127 ? -127 : v);
        dst[k] = (int8_t)v;
    }
    if (tid == 0) dq[row] = rmax / (127.f * 127.f);
}

// temb[j][n] = (j*dt/2)*Wt[n] + bt[n], j = 0..20
__global__ void temb_kern(const float* __restrict__ Wt, const float* __restrict__ bt,
                          float* __restrict__ temb, float half_dt, int total) {
    const int i = blockIdx.x * blockDim.x + threadIdx.x;
    if (i < total) {
        const int j = i >> 9, n = i & 511;
        temb[i] = (j * half_dt) * Wt[n] + bt[n];
    }
}

__global__ void prep_kern(const float* __restrict__ h, const float* __restrict__ temb0,
                          bf16* __restrict__ x0, bf16* __restrict__ hb, int total) {
    const int i = blockIdx.x * blockDim.x + threadIdx.x;
    if (i < total) {
        const float hv = h[i];
        x0[i] = __float2bfloat16(hv + temb0[i & 511]);
        hb[i] = __float2bfloat16(hv);
    }
}

extern "C" void kernel_launch(void* const* d_in, const int* in_sizes, int n_in,
                              void* d_out, int out_size, void* d_ws, size_t ws_size,
                              hipStream_t stream) {
    const float* h_in = (const float*)d_in[0];
    const float* W1 = (const float*)d_in[1];
    const float* b1 = (const float*)d_in[2];
    const float* W2 = (const float*)d_in[3];
    const float* b2 = (const float*)d_in[4];
    const float* W3 = (const float*)d_in[5];
    const float* b3 = (const float*)d_in[6];
    const float* Wt = (const float*)d_in[7];
    const float* bt = (const float*)d_in[8];
    // n_steps (d_in[9]) is a fixed Python scalar = 10.
    const int B = 8192, H = 512, H2 = 1024, NS = 10;
    const float dt = 1.f / NS;

    char* ws = (char*)d_ws;
    auto alloc = [&](size_t bytes) {
        char* p = ws;
        ws += (bytes + 255) & ~(size_t)255;
        return p;
    };
    bf16* W1b = (bf16*)alloc((size_t)H2 * H * 2);
    int8_t* W2i = (int8_t*)alloc((size_t)H2 * H2);      // i8, per-row scaled
    float* dq   = (float*)alloc((size_t)H2 * 4);        // per-row dequant
    bf16* W3b = (bf16*)alloc((size_t)H * H2 * 2);
    bf16* x0b = (bf16*)alloc((size_t)B * H * 2);
    int8_t* x1i = (int8_t*)alloc((size_t)B * H2);       // i8 tanh outputs *127
    bf16* x2b = (bf16*)alloc((size_t)B * H2 * 2);
    bf16* kacc = (bf16*)alloc((size_t)B * H * 2);
    bf16* hb   = (bf16*)alloc((size_t)B * H * 2);
    float* temb = (float*)alloc((size_t)21 * H * 4);
    float* hbuf = (float*)d_out;  // h ping-pongs through d_out (fp32)

    {
        int n = H2 * H;
        f2b_kern<<<(n + 255) / 256, 256, 0, stream>>>(W1, W1b, n);
        quantW2_row<<<H2, 256, 0, stream>>>(W2, H2, W2i, dq);
        n = H * H2;
        f2b_kern<<<(n + 255) / 256, 256, 0, stream>>>(W3, W3b, n);
    }
    {
        const int total = 21 * H;
        temb_kern<<<(total + 255) / 256, 256, 0, stream>>>(Wt, bt, temb, dt * 0.5f, total);
    }
    {
        const int total = B * H;
        prep_kern<<<(total + 255) / 256, 256, 0, stream>>>(h_in, temb, x0b, hb, total);
    }

    const dim3 blk256(256);
    const dim3 g12(H2 / 128, B / 128);  // 8 x 64 = 512 blocks (2/CU)
    const dim3 g3(H / 64, B / 64);      // 8 x 128 = 1024 blocks (4/CU)

    for (int s = 0; s < NS; ++s) {
        const float* hs = (s == 0) ? h_in : hbuf;
        const float* tmid = temb + (size_t)(2 * s + 1) * H;
        const float* tend = temb + (size_t)(2 * s + 2) * H;
        for (int e = 0; e < 4; ++e) {
            gemm_tanh4<<<g12, blk256, 0, stream>>>(x0b, W1b, b1, x1i, H, H2);
            gemm_tanh_i8<<<g12, blk256, 0, stream>>>(x1i, W2i, dq, b2, x2b, H2, H2);
            if (e == 0)
                gemm_k<<<g3, blk256, 0, stream>>>(x2b, W3b, b3, H2, kacc, hb, hs,
                                                  nullptr, nullptr, x0b, tmid,
                                                  dt * 0.5f, 0.f, 0);
            else if (e == 1)
                gemm_k<<<g3, blk256, 0, stream>>>(x2b, W3b, b3, H2, kacc, hb, hs,
                                                  nullptr, nullptr, x0b, tmid,
                                                  dt * 0.5f, 0.f, 1);
            else if (e == 2)
                gemm_k<<<g3, blk256, 0, stream>>>(x2b, W3b, b3, H2, kacc, hb, hs,
                                                  nullptr, nullptr, x0b, tend,
                                                  dt, 0.f, 1);
            else
                gemm_k<<<g3, blk256, 0, stream>>>(x2b, W3b, b3, H2, kacc, hb, hs,
                                                  hbuf, hb,
                                                  (s == NS - 1) ? nullptr : x0b,
                                                  tend, 0.f, dt / 6.f, 2);
        }
    }
}